// Round 10
// baseline (367.335 us; speedup 1.0000x reference)
//
#include <hip/hip_runtime.h>
#include <hip/hip_bf16.h>

typedef __attribute__((ext_vector_type(8))) short bf16x8;
typedef __attribute__((ext_vector_type(4))) float f32x4;

#define B_ 2
#define S_ 2048
#define D_ 1024
#define H_ 16
#define HD_ 64
#define M_ 4096
#define NEGV (-10000.0f)

static __device__ __forceinline__ unsigned short f2bf(float x) {
  __hip_bfloat16 h = __float2bfloat16(x);
  return *reinterpret_cast<unsigned short*>(&h);
}

static __device__ __forceinline__ bf16x8 cvt8(const float* p) {
  float4 a = *reinterpret_cast<const float4*>(p);
  float4 b = *reinterpret_cast<const float4*>(p + 4);
  bf16x8 r;
  r[0] = (short)f2bf(a.x); r[1] = (short)f2bf(a.y);
  r[2] = (short)f2bf(a.z); r[3] = (short)f2bf(a.w);
  r[4] = (short)f2bf(b.x); r[5] = (short)f2bf(b.y);
  r[6] = (short)f2bf(b.z); r[7] = (short)f2bf(b.w);
  return r;
}

// C = A(4096,1024) @ B(1024,1024)^T, bf16 MFMA, f32 accumulate. BK=64.
// AF32/BF32: operand is f32 (cvt on stage); else bf16.
// MODE 0: f32 row-major (final output; d_out is FLOAT32)
// MODE 1: bf16 head-split dst[((b*H+h)*S + s)*HD + d]   (Q, K)
// MODE 2: bf16 transposed  dst[((b*H+h)*HD + d)*S + s]   (V)
// HSPLIT: A is bf16 stored head-split (ctx from attention).
template<int MODE, bool AF32, bool BF32, bool HSPLIT>
__global__ __launch_bounds__(256) void gemm_bt(const void* __restrict__ Av,
                                               const void* __restrict__ Bv,
                                               void* __restrict__ Cout) {
  constexpr int BK = 64, LDT = 72;  // +8 pad: row stride 144B -> 2-way alias
  constexpr int K = 1024, N = 1024;
  __shared__ unsigned short Asm[128 * LDT];   // 18 KB
  __shared__ unsigned short Bsm[128 * LDT];   // 18 KB
  const int tid = threadIdx.x;
  const int lane = tid & 63, wid = tid >> 6;
  const int wm = wid >> 1, wn = wid & 1;
  const int l15 = lane & 15, l4 = lane >> 4;
  const int m0 = blockIdx.y * 128, n0 = blockIdx.x * 128;
  f32x4 acc[4][4] = {};

  for (int k0 = 0; k0 < K; k0 += BK) {
    __syncthreads();
#pragma unroll
    for (int i = 0; i < 4; ++i) {
      int idx = tid + 256 * i;          // 1024 chunks of 8 elems = 128x64 tile
      int row = idx >> 3, k8 = (idx & 7) * 8;
      bf16x8 va, vb;
      if constexpr (AF32) {
        va = cvt8((const float*)Av + (size_t)(m0 + row) * K + k0 + k8);
      } else if constexpr (HSPLIT) {
        const int m = m0 + row, kk = k0 + k8;
        const int bb = m >> 11, s = m & 2047;
        va = *reinterpret_cast<const bf16x8*>(
            (const unsigned short*)Av +
            (((size_t)(bb * H_ + (kk >> 6)) * S_ + s) * HD_ + (kk & 63)));
      } else {
        va = *reinterpret_cast<const bf16x8*>((const unsigned short*)Av + (size_t)(m0 + row) * K + k0 + k8);
      }
      if constexpr (BF32) {
        vb = cvt8((const float*)Bv + (size_t)(n0 + row) * K + k0 + k8);
      } else {
        vb = *reinterpret_cast<const bf16x8*>((const unsigned short*)Bv + (size_t)(n0 + row) * K + k0 + k8);
      }
      *reinterpret_cast<bf16x8*>(&Asm[row * LDT + k8]) = va;
      *reinterpret_cast<bf16x8*>(&Bsm[row * LDT + k8]) = vb;
    }
    __syncthreads();
#pragma unroll
    for (int kk = 0; kk < 2; ++kk) {
      bf16x8 af[4], bfr[4];
#pragma unroll
      for (int f = 0; f < 4; ++f) {
        af[f]  = *reinterpret_cast<const bf16x8*>(&Asm[(wm * 64 + f * 16 + l15) * LDT + kk * 32 + l4 * 8]);
        bfr[f] = *reinterpret_cast<const bf16x8*>(&Bsm[(wn * 64 + f * 16 + l15) * LDT + kk * 32 + l4 * 8]);
      }
#pragma unroll
      for (int fm = 0; fm < 4; ++fm)
#pragma unroll
        for (int fn = 0; fn < 4; ++fn)
          acc[fm][fn] = __builtin_amdgcn_mfma_f32_16x16x32_bf16(af[fm], bfr[fn], acc[fm][fn], 0, 0, 0);
    }
  }

#pragma unroll
  for (int fm = 0; fm < 4; ++fm) {
#pragma unroll
    for (int fn = 0; fn < 4; ++fn) {
      const int mg0 = m0 + wm * 64 + fm * 16 + l4 * 4;   // rows mg0..mg0+3
      const int ng  = n0 + wn * 64 + fn * 16 + l15;
      if constexpr (MODE == 0) {
        float* C = (float*)Cout;                    // FLOAT32 final output
#pragma unroll
        for (int r = 0; r < 4; ++r)
          C[(size_t)(mg0 + r) * N + ng] = acc[fm][fn][r];
      } else if constexpr (MODE == 1) {
        unsigned short* C = (unsigned short*)Cout;
        const int bidx = mg0 >> 11, s = mg0 & 2047;
        const int h = ng >> 6, d = ng & 63;
#pragma unroll
        for (int r = 0; r < 4; ++r)
          C[((size_t)((bidx * H_ + h) * S_ + s + r)) * HD_ + d] = f2bf(acc[fm][fn][r]);
      } else {
        unsigned short* C = (unsigned short*)Cout;
        const int bidx = mg0 >> 11, s = mg0 & 2047;
        const int h = ng >> 6, d = ng & 63;
        ushort4 pk;
        pk.x = f2bf(acc[fm][fn][0]); pk.y = f2bf(acc[fm][fn][1]);
        pk.z = f2bf(acc[fm][fn][2]); pk.w = f2bf(acc[fm][fn][3]);
        *reinterpret_cast<ushort4*>(&C[((size_t)((bidx * H_ + h) * HD_ + d)) * S_ + s]) = pk;
      }
    }
  }
}

// Flash-style MFMA attention, NO K/V STAGING: K and V fragments are read
// directly from global (per-head K+V = 512 KB, L1/L2-resident, reused by 32
// blocks). Zero __syncthreads in the K-loop -- waves free-run, softmax chains
// from different waves overlap. Only Psm (wave-private) lives in LDS.
// Heavy-first dispatch: q0 = (31 - blockIdx.x)*64 so 16-tile blocks start
// first. Causal tile-skip exact (see r8). ctx may alias Qh.
__global__ __launch_bounds__(256) void attn_fwd(const unsigned short* Qh,
                                                const unsigned short* __restrict__ Kh,
                                                const unsigned short* __restrict__ Vt,
                                                const int* __restrict__ attn_mask,
                                                const int* __restrict__ mask_future,
                                                unsigned short* ctx) {
  constexpr int KVB = 128;
  constexpr int LDP = 136;   // P per-wave [16][128+8]
  __shared__ unsigned short Psm[4][16 * LDP];   // 17408 B total
  __shared__ int s_any;
  const int tid = threadIdx.x, lane = tid & 63, wid = tid >> 6;
  const int l15 = lane & 15, l4 = lane >> 4;
  const int bh = blockIdx.y, b = bh >> 4;
  const int q0 = ((int)gridDim.x - 1 - (int)blockIdx.x) * 64;  // heavy first
  const bool causal = (mask_future[0] != 0);

  if (tid == 0) s_any = 0;
  __syncthreads();
  for (int i = tid; i <= q0; i += 256)
    if (attn_mask[b * S_ + i]) s_any = 1;
  __syncthreads();
  const int kb_end = (causal && s_any) ? (q0 + 64) : S_;

  const unsigned short* Qb = Qh + (size_t)bh * S_ * HD_;
  const unsigned short* Kb = Kh + (size_t)bh * S_ * HD_;
  const unsigned short* Vb = Vt + (size_t)bh * HD_ * S_;
  const int* mrow = attn_mask + b * S_;

  const int qrow = q0 + wid * 16 + l15;
  const bf16x8 qf0 = *reinterpret_cast<const bf16x8*>(&Qb[(size_t)qrow * HD_ + l4 * 8]);
  const bf16x8 qf1 = *reinterpret_cast<const bf16x8*>(&Qb[(size_t)qrow * HD_ + 32 + l4 * 8]);

  float m_run[4], l_run[4];
  f32x4 o[4] = {};
#pragma unroll
  for (int r = 0; r < 4; ++r) { m_run[r] = -1e30f; l_run[r] = 0.f; }

  unsigned short* Pw = &Psm[wid][0];

  for (int kb = 0; kb < kb_end; kb += KVB) {
    // per-tile mask -> registers (8 bools, shared across the r-loop)
    int mk[8];
#pragma unroll
    for (int nf = 0; nf < 8; ++nf) mk[nf] = mrow[kb + nf * 16 + l15];

    // QK^T: B-fragment = 16B contiguous global read of K row (L1/L2 hit)
    f32x4 sc[8];
#pragma unroll
    for (int nf = 0; nf < 8; ++nf) {
      const unsigned short* kr = &Kb[(size_t)(kb + nf * 16 + l15) * HD_];
      bf16x8 kf0 = *reinterpret_cast<const bf16x8*>(kr + l4 * 8);
      bf16x8 kf1 = *reinterpret_cast<const bf16x8*>(kr + 32 + l4 * 8);
      f32x4 z = {};
      z = __builtin_amdgcn_mfma_f32_16x16x32_bf16(qf0, kf0, z, 0, 0, 0);
      z = __builtin_amdgcn_mfma_f32_16x16x32_bf16(qf1, kf1, z, 0, 0, 0);
      sc[nf] = z;
    }

#pragma unroll
    for (int r = 0; r < 4; ++r) {
      const int rowg = q0 + wid * 16 + l4 * 4 + r;
      float mx = -1e30f;
      float pv[8];
#pragma unroll
      for (int nf = 0; nf < 8; ++nf) {
        const int colg = kb + nf * 16 + l15;
        float vv = sc[nf][r] * 0.125f;               // 1/sqrt(64)
        if (causal && colg > rowg) vv += NEGV;       // causal bias (additive)
        if (mk[nf] == 0) vv = NEGV;                  // pad mask (replace)
        pv[nf] = vv;
        mx = fmaxf(mx, vv);
      }
      mx = fmaxf(mx, __shfl_xor(mx, 1));
      mx = fmaxf(mx, __shfl_xor(mx, 2));
      mx = fmaxf(mx, __shfl_xor(mx, 4));
      mx = fmaxf(mx, __shfl_xor(mx, 8));
      const float m_new = fmaxf(m_run[r], mx);
      const float scale = __expf(m_run[r] - m_new);
      float s_loc = 0.f;
#pragma unroll
      for (int nf = 0; nf < 8; ++nf) {
        float e = __expf(pv[nf] - m_new);
        s_loc += e;
        Pw[(l4 * 4 + r) * LDP + nf * 16 + l15] = f2bf(e);
      }
      s_loc += __shfl_xor(s_loc, 1);
      s_loc += __shfl_xor(s_loc, 2);
      s_loc += __shfl_xor(s_loc, 4);
      s_loc += __shfl_xor(s_loc, 8);
      l_run[r] = l_run[r] * scale + s_loc;
      m_run[r] = m_new;
#pragma unroll
      for (int nf2 = 0; nf2 < 4; ++nf2) o[nf2][r] *= scale;
    }

    // PV: P from wave-private LDS (lgkmcnt only), V direct from global
#pragma unroll
    for (int nf2 = 0; nf2 < 4; ++nf2) {
      const unsigned short* vr = &Vb[(size_t)(nf2 * 16 + l15) * S_ + kb];
#pragma unroll
      for (int kk = 0; kk < 4; ++kk) {
        bf16x8 pf = *reinterpret_cast<const bf16x8*>(&Pw[l15 * LDP + kk * 32 + l4 * 8]);
        bf16x8 vf = *reinterpret_cast<const bf16x8*>(vr + kk * 32 + l4 * 8);
        o[nf2] = __builtin_amdgcn_mfma_f32_16x16x32_bf16(pf, vf, o[nf2], 0, 0, 0);
      }
    }
  }

  // ctx write: head-split layout, rows q0..q0+63 of slice bh (in-place over Qh)
#pragma unroll
  for (int nf2 = 0; nf2 < 4; ++nf2)
#pragma unroll
    for (int r = 0; r < 4; ++r) {
      const int rowg = q0 + wid * 16 + l4 * 4 + r;
      float vv = o[nf2][r] / l_run[r];
      ctx[((size_t)bh * S_ + rowg) * HD_ + nf2 * 16 + l15] = f2bf(vv);
    }
}

extern "C" void kernel_launch(void* const* d_in, const int* in_sizes, int n_in,
                              void* d_out, int out_size, void* d_ws, size_t ws_size,
                              hipStream_t stream) {
  const float* q = (const float*)d_in[0];
  const float* k = (const float*)d_in[1];
  const float* v = (const float*)d_in[2];
  const int* attn_mask = (const int*)d_in[3];
  const float* Wq = (const float*)d_in[4];
  const float* Wk = (const float*)d_in[5];
  const float* Wv = (const float*)d_in[6];
  const float* Wo = (const float*)d_in[7];
  const int* mask_future = (const int*)d_in[8];

  // d_out is FLOAT32 (16.78 MB). ws usage: 16.78 MB.
  //   ws0: Qh bf16 (Q-proj) -> overwritten IN PLACE by ctx (head-split)
  //   ws1: Kh bf16 (K-proj)
  //   d_out first half: Vt bf16 (V-proj, transposed) -> dead after attn,
  //        then the O-proj GEMM overwrites ALL of d_out with f32 output.
  const size_t n16 = (size_t)M_ * D_;
  unsigned short* ws0 = (unsigned short*)d_ws;
  unsigned short* ws1 = ws0 + n16;
  unsigned short* Vt  = (unsigned short*)d_out;
  float* out = (float*)d_out;
  (void)in_sizes; (void)n_in; (void)out_size; (void)ws_size;

  dim3 gg(D_ / 128, M_ / 128);   // (8, 32)
  gemm_bt<1, true,  true,  false><<<gg, 256, 0, stream>>>(q, Wq, ws0);
  gemm_bt<1, true,  true,  false><<<gg, 256, 0, stream>>>(k, Wk, ws1);
  gemm_bt<2, true,  true,  false><<<gg, 256, 0, stream>>>(v, Wv, Vt);
  attn_fwd<<<dim3(S_ / 64, B_ * H_), 256, 0, stream>>>(ws0, ws1, Vt, attn_mask, mask_future, ws0);
  gemm_bt<0, false, true,  true ><<<gg, 256, 0, stream>>>(ws0, Wo, out);
}

// Round 11
// 257.722 us; speedup vs baseline: 1.4253x; 1.4253x over previous
//
#include <hip/hip_runtime.h>
#include <hip/hip_bf16.h>

typedef __attribute__((ext_vector_type(8))) short bf16x8;
typedef __attribute__((ext_vector_type(4))) short bf16x4;
typedef __attribute__((ext_vector_type(4))) float f32x4;

#define B_ 2
#define S_ 2048
#define D_ 1024
#define H_ 16
#define HD_ 64
#define M_ 4096
#define NEGV (-10000.0f)

#if __has_builtin(__builtin_amdgcn_mfma_f32_16x16x16bf16_1k)
#define HAVE_MFMA16 1
#else
#define HAVE_MFMA16 0
#endif

static __device__ __forceinline__ unsigned short f2bf(float x) {
  __hip_bfloat16 h = __float2bfloat16(x);
  return *reinterpret_cast<unsigned short*>(&h);
}

static __device__ __forceinline__ bf16x8 cvt8(const float* p) {
  float4 a = *reinterpret_cast<const float4*>(p);
  float4 b = *reinterpret_cast<const float4*>(p + 4);
  bf16x8 r;
  r[0] = (short)f2bf(a.x); r[1] = (short)f2bf(a.y);
  r[2] = (short)f2bf(a.z); r[3] = (short)f2bf(a.w);
  r[4] = (short)f2bf(b.x); r[5] = (short)f2bf(b.y);
  r[6] = (short)f2bf(b.z); r[7] = (short)f2bf(b.w);
  return r;
}

// C = A(4096,1024) @ B(1024,1024)^T, bf16 MFMA, f32 accumulate. BK=64.
// (unchanged from round 9 -- this round isolates the attention rewrite)
template<int MODE, bool AF32, bool BF32, bool HSPLIT>
__global__ __launch_bounds__(256) void gemm_bt(const void* __restrict__ Av,
                                               const void* __restrict__ Bv,
                                               void* __restrict__ Cout) {
  constexpr int BK = 64, LDT = 72;
  constexpr int K = 1024, N = 1024;
  __shared__ unsigned short Asm[128 * LDT];
  __shared__ unsigned short Bsm[128 * LDT];
  const int tid = threadIdx.x;
  const int lane = tid & 63, wid = tid >> 6;
  const int wm = wid >> 1, wn = wid & 1;
  const int l15 = lane & 15, l4 = lane >> 4;
  const int m0 = blockIdx.y * 128, n0 = blockIdx.x * 128;
  f32x4 acc[4][4] = {};

  for (int k0 = 0; k0 < K; k0 += BK) {
    __syncthreads();
#pragma unroll
    for (int i = 0; i < 4; ++i) {
      int idx = tid + 256 * i;
      int row = idx >> 3, k8 = (idx & 7) * 8;
      bf16x8 va, vb;
      if constexpr (AF32) {
        va = cvt8((const float*)Av + (size_t)(m0 + row) * K + k0 + k8);
      } else if constexpr (HSPLIT) {
        const int m = m0 + row, kk = k0 + k8;
        const int bb = m >> 11, s = m & 2047;
        va = *reinterpret_cast<const bf16x8*>(
            (const unsigned short*)Av +
            (((size_t)(bb * H_ + (kk >> 6)) * S_ + s) * HD_ + (kk & 63)));
      } else {
        va = *reinterpret_cast<const bf16x8*>((const unsigned short*)Av + (size_t)(m0 + row) * K + k0 + k8);
      }
      if constexpr (BF32) {
        vb = cvt8((const float*)Bv + (size_t)(n0 + row) * K + k0 + k8);
      } else {
        vb = *reinterpret_cast<const bf16x8*>((const unsigned short*)Bv + (size_t)(n0 + row) * K + k0 + k8);
      }
      *reinterpret_cast<bf16x8*>(&Asm[row * LDT + k8]) = va;
      *reinterpret_cast<bf16x8*>(&Bsm[row * LDT + k8]) = vb;
    }
    __syncthreads();
#pragma unroll
    for (int kk = 0; kk < 2; ++kk) {
      bf16x8 af[4], bfr[4];
#pragma unroll
      for (int f = 0; f < 4; ++f) {
        af[f]  = *reinterpret_cast<const bf16x8*>(&Asm[(wm * 64 + f * 16 + l15) * LDT + kk * 32 + l4 * 8]);
        bfr[f] = *reinterpret_cast<const bf16x8*>(&Bsm[(wn * 64 + f * 16 + l15) * LDT + kk * 32 + l4 * 8]);
      }
#pragma unroll
      for (int fm = 0; fm < 4; ++fm)
#pragma unroll
        for (int fn = 0; fn < 4; ++fn)
          acc[fm][fn] = __builtin_amdgcn_mfma_f32_16x16x32_bf16(af[fm], bfr[fn], acc[fm][fn], 0, 0, 0);
    }
  }

#pragma unroll
  for (int fm = 0; fm < 4; ++fm) {
#pragma unroll
    for (int fn = 0; fn < 4; ++fn) {
      const int mg0 = m0 + wm * 64 + fm * 16 + l4 * 4;
      const int ng  = n0 + wn * 64 + fn * 16 + l15;
      if constexpr (MODE == 0) {
        float* C = (float*)Cout;
#pragma unroll
        for (int r = 0; r < 4; ++r)
          C[(size_t)(mg0 + r) * N + ng] = acc[fm][fn][r];
      } else if constexpr (MODE == 1) {
        unsigned short* C = (unsigned short*)Cout;
        const int bidx = mg0 >> 11, s = mg0 & 2047;
        const int h = ng >> 6, d = ng & 63;
#pragma unroll
        for (int r = 0; r < 4; ++r)
          C[((size_t)((bidx * H_ + h) * S_ + s + r)) * HD_ + d] = f2bf(acc[fm][fn][r]);
      } else {
        unsigned short* C = (unsigned short*)Cout;
        const int bidx = mg0 >> 11, s = mg0 & 2047;
        const int h = ng >> 6, d = ng & 63;
        ushort4 pk;
        pk.x = f2bf(acc[fm][fn][0]); pk.y = f2bf(acc[fm][fn][1]);
        pk.z = f2bf(acc[fm][fn][2]); pk.w = f2bf(acc[fm][fn][3]);
        *reinterpret_cast<ushort4*>(&C[((size_t)((bidx * H_ + h) * HD_ + d)) * S_ + s]) = pk;
      }
    }
  }
}

// Flash MFMA attention, SWAPPED QK^T (P^T in regs; lane-local softmax).
// z = mfma(K_frag, Q_frag) -> D[key=(l4)*4+r][q=l15]: each lane holds the
// P-row of q = l15 across keys {nf*16 + l4*4 + r}. Row-reduce = shfl_xor
// 16,32 only. PV uses mfma_f32_16x16x16bf16_1k whose A-frag k-elems are
// l4*4..+3 -- exactly the keys this lane holds: NO cross-lane move, NO P-LDS.
// KVB=128 staged in LDS (reg-prefetched), 2 barriers/tile, LDS 35.8 KB ->
// 4 blocks/CU. Causal tile-skip exact (r8). ctx may alias Qh.
__global__ __launch_bounds__(256) void attn_fwd(const unsigned short* Qh,
                                                const unsigned short* __restrict__ Kh,
                                                const unsigned short* __restrict__ Vt,
                                                const int* __restrict__ attn_mask,
                                                const int* __restrict__ mask_future,
                                                unsigned short* ctx) {
  constexpr int KVB = 128;
  constexpr int LDK = 72;    // K tile [128][64+8]
  constexpr int LDV = 136;   // V tile d-major [64][128+8]
  __shared__ unsigned short Ksm[KVB * LDK];     // 18432 B
  __shared__ unsigned short Vsm[64 * LDV];      // 17408 B
#if !HAVE_MFMA16
  __shared__ unsigned short Psm[4][16 * LDV];
#endif
  __shared__ int s_any;
  const int tid = threadIdx.x, lane = tid & 63, wid = tid >> 6;
  const int l15 = lane & 15, l4 = lane >> 4;
  const int bh = blockIdx.y, b = bh >> 4;
  const int q0 = ((int)gridDim.x - 1 - (int)blockIdx.x) * 64;  // heavy first
  const bool causal = (mask_future[0] != 0);

  if (tid == 0) s_any = 0;
  __syncthreads();
  for (int i = tid; i <= q0; i += 256)
    if (attn_mask[b * S_ + i]) s_any = 1;
  __syncthreads();
  const int kb_end = (causal && s_any) ? (q0 + 64) : S_;

  const unsigned short* Qb = Qh + (size_t)bh * S_ * HD_;
  const unsigned short* Kb = Kh + (size_t)bh * S_ * HD_;
  const unsigned short* Vb = Vt + (size_t)bh * HD_ * S_;
  const int* mrow = attn_mask + b * S_;

  const int qrow = q0 + wid * 16 + l15;   // this lane's q-row
  const bf16x8 qf0 = *reinterpret_cast<const bf16x8*>(&Qb[(size_t)qrow * HD_ + l4 * 8]);
  const bf16x8 qf1 = *reinterpret_cast<const bf16x8*>(&Qb[(size_t)qrow * HD_ + 32 + l4 * 8]);

  float m_run = -1e30f, l_run = 0.f;      // scalar state for q = l15
  f32x4 o[4] = {};                        // o[nf2][r]: q=wid*16+l4*4+r, d=nf2*16+l15

  // prefetch registers: K 128x64 and V 64x128 = 1024 chunks of 8 each
  bf16x8 kreg[4], vreg[4];
  {
#pragma unroll
    for (int j = 0; j < 4; ++j) {
      const int idx = tid + 256 * j;
      kreg[j] = *reinterpret_cast<const bf16x8*>(&Kb[(size_t)(idx >> 3) * HD_ + (idx & 7) * 8]);
      vreg[j] = *reinterpret_cast<const bf16x8*>(&Vb[(size_t)(idx >> 4) * S_ + (idx & 15) * 8]);
    }
  }

  for (int kb = 0; kb < kb_end; kb += KVB) {
    __syncthreads();   // all waves done reading previous tile's LDS
#pragma unroll
    for (int j = 0; j < 4; ++j) {
      const int idx = tid + 256 * j;
      *reinterpret_cast<bf16x8*>(&Ksm[(idx >> 3) * LDK + (idx & 7) * 8]) = kreg[j];
      *reinterpret_cast<bf16x8*>(&Vsm[(idx >> 4) * LDV + (idx & 15) * 8]) = vreg[j];
    }
    __syncthreads();

    if (kb + KVB < kb_end) {
      const int kn = kb + KVB;
#pragma unroll
      for (int j = 0; j < 4; ++j) {
        const int idx = tid + 256 * j;
        kreg[j] = *reinterpret_cast<const bf16x8*>(&Kb[(size_t)(kn + (idx >> 3)) * HD_ + (idx & 7) * 8]);
        vreg[j] = *reinterpret_cast<const bf16x8*>(&Vb[(size_t)(idx >> 4) * S_ + kn + (idx & 15) * 8]);
      }
    }

    // QK^T swapped: sc[nf] = P^T fragment; lane holds q=l15, keys nf*16+l4*4+r
    f32x4 sc[8];
#pragma unroll
    for (int nf = 0; nf < 8; ++nf) {
      bf16x8 kf0 = *reinterpret_cast<const bf16x8*>(&Ksm[(nf * 16 + l15) * LDK + l4 * 8]);
      bf16x8 kf1 = *reinterpret_cast<const bf16x8*>(&Ksm[(nf * 16 + l15) * LDK + 32 + l4 * 8]);
      f32x4 z = {};
      z = __builtin_amdgcn_mfma_f32_16x16x32_bf16(kf0, qf0, z, 0, 0, 0);
      z = __builtin_amdgcn_mfma_f32_16x16x32_bf16(kf1, qf1, z, 0, 0, 0);
      sc[nf] = z;
    }

    // lane-local softmax over this lane's 32 keys (row q = l15)
    float p[8][4];
    float mx = -1e30f;
#pragma unroll
    for (int nf = 0; nf < 8; ++nf) {
      const int4 mk4 = *reinterpret_cast<const int4*>(&mrow[kb + nf * 16 + l4 * 4]);
      const int kbase = kb + nf * 16 + l4 * 4;
#pragma unroll
      for (int r = 0; r < 4; ++r) {
        float vv = sc[nf][r] * 0.125f;                    // 1/sqrt(64)
        if (causal && (kbase + r) > qrow) vv += NEGV;     // causal (additive)
        const int mkr = (r == 0) ? mk4.x : (r == 1) ? mk4.y : (r == 2) ? mk4.z : mk4.w;
        if (mkr == 0) vv = NEGV;                          // pad mask (replace)
        p[nf][r] = vv;
        mx = fmaxf(mx, vv);
      }
    }
    mx = fmaxf(mx, __shfl_xor(mx, 16));
    mx = fmaxf(mx, __shfl_xor(mx, 32));
    const float m_new = fmaxf(m_run, mx);
    const float scale = __expf(m_run - m_new);
    float s_loc = 0.f;
#pragma unroll
    for (int nf = 0; nf < 8; ++nf)
#pragma unroll
      for (int r = 0; r < 4; ++r) {
        float e = __expf(p[nf][r] - m_new);
        p[nf][r] = e;
        s_loc += e;
      }
    s_loc += __shfl_xor(s_loc, 16);
    s_loc += __shfl_xor(s_loc, 32);
    l_run = l_run * scale + s_loc;
    m_run = m_new;

    // redistribute rescale factor to O layout (q = l4*4+r lives at lane l4*4+r)
    float sq[4];
#pragma unroll
    for (int r = 0; r < 4; ++r) sq[r] = __shfl(scale, l4 * 4 + r);
#pragma unroll
    for (int nf2 = 0; nf2 < 4; ++nf2)
#pragma unroll
      for (int r = 0; r < 4; ++r) o[nf2][r] *= sq[r];

#if HAVE_MFMA16
    // pack P to bf16x4 A-frags (k-elems l4*4..+3 = exactly this lane's keys)
    bf16x4 pk[8];
#pragma unroll
    for (int nf = 0; nf < 8; ++nf) {
      bf16x4 t;
      t[0] = (short)f2bf(p[nf][0]); t[1] = (short)f2bf(p[nf][1]);
      t[2] = (short)f2bf(p[nf][2]); t[3] = (short)f2bf(p[nf][3]);
      pk[nf] = t;
    }
    // PV: o[q][d] += P[q][k] V[k][d]; V-frag lane l15 = d-row, k = nf*16+l4*4
#pragma unroll
    for (int nf2 = 0; nf2 < 4; ++nf2) {
#pragma unroll
      for (int nf = 0; nf < 8; ++nf) {
        bf16x4 vf = *reinterpret_cast<const bf16x4*>(&Vsm[(nf2 * 16 + l15) * LDV + nf * 16 + l4 * 4]);
        o[nf2] = __builtin_amdgcn_mfma_f32_16x16x16bf16_1k(pk[nf], vf, o[nf2], 0, 0, 0);
      }
    }
#else
    // fallback: wave-private LDS roundtrip to A-frag layout
    unsigned short* Pw = &Psm[wid][0];
#pragma unroll
    for (int nf = 0; nf < 8; ++nf)
#pragma unroll
      for (int r = 0; r < 4; ++r)
        Pw[l15 * LDV + nf * 16 + l4 * 4 + r] = f2bf(p[nf][r]);
#pragma unroll
    for (int nf2 = 0; nf2 < 4; ++nf2) {
#pragma unroll
      for (int kk = 0; kk < 4; ++kk) {
        bf16x8 pf = *reinterpret_cast<const bf16x8*>(&Pw[l15 * LDV + kk * 32 + l4 * 8]);
        bf16x8 vf = *reinterpret_cast<const bf16x8*>(&Vsm[(nf2 * 16 + l15) * LDV + kk * 32 + l4 * 8]);
        o[nf2] = __builtin_amdgcn_mfma_f32_16x16x32_bf16(pf, vf, o[nf2], 0, 0, 0);
      }
    }
#endif
  }

  // epilogue: 1/l for q=l4*4+r lives at lane l4*4+r
  const float linv = 1.f / l_run;
  float lq[4];
#pragma unroll
  for (int r = 0; r < 4; ++r) lq[r] = __shfl(linv, l4 * 4 + r);
#pragma unroll
  for (int nf2 = 0; nf2 < 4; ++nf2)
#pragma unroll
    for (int r = 0; r < 4; ++r) {
      const int rowg = q0 + wid * 16 + l4 * 4 + r;
      ctx[((size_t)bh * S_ + rowg) * HD_ + nf2 * 16 + l15] = f2bf(o[nf2][r] * lq[r]);
    }
}

extern "C" void kernel_launch(void* const* d_in, const int* in_sizes, int n_in,
                              void* d_out, int out_size, void* d_ws, size_t ws_size,
                              hipStream_t stream) {
  const float* q = (const float*)d_in[0];
  const float* k = (const float*)d_in[1];
  const float* v = (const float*)d_in[2];
  const int* attn_mask = (const int*)d_in[3];
  const float* Wq = (const float*)d_in[4];
  const float* Wk = (const float*)d_in[5];
  const float* Wv = (const float*)d_in[6];
  const float* Wo = (const float*)d_in[7];
  const int* mask_future = (const int*)d_in[8];

  // d_out is FLOAT32 (16.78 MB). ws usage: 16.78 MB.
  //   ws0: Qh bf16 (Q-proj) -> overwritten IN PLACE by ctx (head-split)
  //   ws1: Kh bf16 (K-proj)
  //   d_out first half: Vt bf16 (V-proj, transposed) -> dead after attn,
  //        then the O-proj GEMM overwrites ALL of d_out with f32 output.
  const size_t n16 = (size_t)M_ * D_;
  unsigned short* ws0 = (unsigned short*)d_ws;
  unsigned short* ws1 = ws0 + n16;
  unsigned short* Vt  = (unsigned short*)d_out;
  float* out = (float*)d_out;
  (void)in_sizes; (void)n_in; (void)out_size; (void)ws_size;

  dim3 gg(D_ / 128, M_ / 128);   // (8, 32)
  gemm_bt<1, true,  true,  false><<<gg, 256, 0, stream>>>(q, Wq, ws0);
  gemm_bt<1, true,  true,  false><<<gg, 256, 0, stream>>>(k, Wk, ws1);
  gemm_bt<2, true,  true,  false><<<gg, 256, 0, stream>>>(v, Wv, Vt);
  attn_fwd<<<dim3(S_ / 64, B_ * H_), 256, 0, stream>>>(ws0, ws1, Vt, attn_mask, mask_future, ws0);
  gemm_bt<0, false, true,  true ><<<gg, 256, 0, stream>>>(ws0, Wo, out);
}

// Round 12
// 203.025 us; speedup vs baseline: 1.8093x; 1.2694x over previous
//
#include <hip/hip_runtime.h>
#include <hip/hip_bf16.h>

typedef __attribute__((ext_vector_type(8))) short bf16x8;
typedef __attribute__((ext_vector_type(4))) short bf16x4;
typedef __attribute__((ext_vector_type(4))) float f32x4;

#define B_ 2
#define S_ 2048
#define D_ 1024
#define H_ 16
#define HD_ 64
#define M_ 4096
#define NEGV (-10000.0f)

#if __has_builtin(__builtin_amdgcn_mfma_f32_16x16x16bf16_1k)
#define HAVE_MFMA16 1
#else
#define HAVE_MFMA16 0
#endif

static __device__ __forceinline__ unsigned short f2bf(float x) {
  __hip_bfloat16 h = __float2bfloat16(x);
  return *reinterpret_cast<unsigned short*>(&h);
}

static __device__ __forceinline__ bf16x8 cvt8(const float* p) {
  float4 a = *reinterpret_cast<const float4*>(p);
  float4 b = *reinterpret_cast<const float4*>(p + 4);
  bf16x8 r;
  r[0] = (short)f2bf(a.x); r[1] = (short)f2bf(a.y);
  r[2] = (short)f2bf(a.z); r[3] = (short)f2bf(a.w);
  r[4] = (short)f2bf(b.x); r[5] = (short)f2bf(b.y);
  r[6] = (short)f2bf(b.z); r[7] = (short)f2bf(b.w);
  return r;
}

// ---- shared GEMM core: C128x128 = A(128,K) @ B(128,K)^T over K=1024 ----
// acc layout: acc[fm][fn][r] -> row m0+wm*64+fm*16+l4*4+r, col n0+wn*64+fn*16+l15
template<bool AF32, bool BF32, bool HSPLIT>
static __device__ __forceinline__ void gemm_core(const void* Av, const void* Bv,
                                                 unsigned short* Asm, unsigned short* Bsm,
                                                 int m0, int n0, f32x4 (*acc)[4]) {
  constexpr int BK = 64, LDT = 72;
  constexpr int K = 1024;
  const int tid = threadIdx.x;
  const int lane = tid & 63, wid = tid >> 6;
  const int wm = wid >> 1, wn = wid & 1;
  const int l15 = lane & 15, l4 = lane >> 4;

  for (int k0 = 0; k0 < K; k0 += BK) {
    __syncthreads();
#pragma unroll
    for (int i = 0; i < 4; ++i) {
      int idx = tid + 256 * i;
      int row = idx >> 3, k8 = (idx & 7) * 8;
      bf16x8 va, vb;
      if constexpr (AF32) {
        va = cvt8((const float*)Av + (size_t)(m0 + row) * K + k0 + k8);
      } else if constexpr (HSPLIT) {
        const int m = m0 + row, kk = k0 + k8;
        const int bb = m >> 11, s = m & 2047;
        va = *reinterpret_cast<const bf16x8*>(
            (const unsigned short*)Av +
            (((size_t)(bb * H_ + (kk >> 6)) * S_ + s) * HD_ + (kk & 63)));
      } else {
        va = *reinterpret_cast<const bf16x8*>((const unsigned short*)Av + (size_t)(m0 + row) * K + k0 + k8);
      }
      if constexpr (BF32) {
        vb = cvt8((const float*)Bv + (size_t)(n0 + row) * K + k0 + k8);
      } else {
        vb = *reinterpret_cast<const bf16x8*>((const unsigned short*)Bv + (size_t)(n0 + row) * K + k0 + k8);
      }
      *reinterpret_cast<bf16x8*>(&Asm[row * LDT + k8]) = va;
      *reinterpret_cast<bf16x8*>(&Bsm[row * LDT + k8]) = vb;
    }
    __syncthreads();
#pragma unroll
    for (int kk = 0; kk < 2; ++kk) {
      bf16x8 af[4], bfr[4];
#pragma unroll
      for (int f = 0; f < 4; ++f) {
        af[f]  = *reinterpret_cast<const bf16x8*>(&Asm[(wm * 64 + f * 16 + l15) * LDT + kk * 32 + l4 * 8]);
        bfr[f] = *reinterpret_cast<const bf16x8*>(&Bsm[(wn * 64 + f * 16 + l15) * LDT + kk * 32 + l4 * 8]);
      }
#pragma unroll
      for (int fm = 0; fm < 4; ++fm)
#pragma unroll
        for (int fn = 0; fn < 4; ++fn)
          acc[fm][fn] = __builtin_amdgcn_mfma_f32_16x16x32_bf16(af[fm], bfr[fn], acc[fm][fn], 0, 0, 0);
    }
  }
}

// merged Q/K/V projections: gridDim.z=3 selects (A,B,dst,mode).
// Stride-256 CU aliasing gives every CU one Q, one K, one V block.
__global__ __launch_bounds__(256) void gemm_qkv3(const float* __restrict__ q,
                                                 const float* __restrict__ k,
                                                 const float* __restrict__ v,
                                                 const float* __restrict__ Wq,
                                                 const float* __restrict__ Wk,
                                                 const float* __restrict__ Wv,
                                                 unsigned short* __restrict__ Qh,
                                                 unsigned short* __restrict__ Kh,
                                                 unsigned short* __restrict__ Vt) {
  constexpr int LDT = 72;
  __shared__ unsigned short Asm[128 * LDT];
  __shared__ unsigned short Bsm[128 * LDT];
  const int z = blockIdx.z;
  const float* A  = (z == 0) ? q  : (z == 1) ? k  : v;
  const float* Bw = (z == 0) ? Wq : (z == 1) ? Wk : Wv;
  const int m0 = blockIdx.y * 128, n0 = blockIdx.x * 128;
  const int lane = threadIdx.x & 63, wid = threadIdx.x >> 6;
  const int wm = wid >> 1, wn = wid & 1;
  const int l15 = lane & 15, l4 = lane >> 4;
  f32x4 acc[4][4] = {};
  gemm_core<true, true, false>(A, Bw, Asm, Bsm, m0, n0, acc);

#pragma unroll
  for (int fm = 0; fm < 4; ++fm) {
#pragma unroll
    for (int fn = 0; fn < 4; ++fn) {
      const int mg0 = m0 + wm * 64 + fm * 16 + l4 * 4;
      const int ng  = n0 + wn * 64 + fn * 16 + l15;
      const int bidx = mg0 >> 11, s = mg0 & 2047;
      const int h = ng >> 6, d = ng & 63;
      if (z < 2) {
        unsigned short* C = (z == 0) ? Qh : Kh;      // MODE 1: head-split
#pragma unroll
        for (int r = 0; r < 4; ++r)
          C[((size_t)((bidx * H_ + h) * S_ + s + r)) * HD_ + d] = f2bf(acc[fm][fn][r]);
      } else {                                       // MODE 2: transposed V
        ushort4 pk;
        pk.x = f2bf(acc[fm][fn][0]); pk.y = f2bf(acc[fm][fn][1]);
        pk.z = f2bf(acc[fm][fn][2]); pk.w = f2bf(acc[fm][fn][3]);
        *reinterpret_cast<ushort4*>(&Vt[((size_t)((bidx * H_ + h) * HD_ + d)) * S_ + s]) = pk;
      }
    }
  }
}

// O-projection: A = head-split bf16 ctx, B = f32 Wo, C = f32 d_out.
__global__ __launch_bounds__(256) void gemm_oproj(const void* __restrict__ Av,
                                                  const void* __restrict__ Bv,
                                                  float* __restrict__ Cout) {
  constexpr int LDT = 72;
  __shared__ unsigned short Asm[128 * LDT];
  __shared__ unsigned short Bsm[128 * LDT];
  const int m0 = blockIdx.y * 128, n0 = blockIdx.x * 128;
  const int lane = threadIdx.x & 63, wid = threadIdx.x >> 6;
  const int wm = wid >> 1, wn = wid & 1;
  const int l15 = lane & 15, l4 = lane >> 4;
  f32x4 acc[4][4] = {};
  gemm_core<false, true, true>(Av, Bv, Asm, Bsm, m0, n0, acc);

#pragma unroll
  for (int fm = 0; fm < 4; ++fm)
#pragma unroll
    for (int fn = 0; fn < 4; ++fn) {
      const int mg0 = m0 + wm * 64 + fm * 16 + l4 * 4;
      const int ng  = n0 + wn * 64 + fn * 16 + l15;
#pragma unroll
      for (int r = 0; r < 4; ++r)
        Cout[(size_t)(mg0 + r) * 1024 + ng] = acc[fm][fn][r];
    }
}

// Flash MFMA attention (swapped QK^T, lane-local softmax, K=16 PV).
// DIAGONAL q-tile swizzle: q0 = ((bx+by)&31)*64 -- the 4 blocks aliasing to
// one CU (stride-256) get q-tile indices spread by {0,8,16,24}, balancing
// per-CU tile load (was: all 4 identical -> worst CU 64 tile-rounds, now 40).
__global__ __launch_bounds__(256) void attn_fwd(const unsigned short* Qh,
                                                const unsigned short* __restrict__ Kh,
                                                const unsigned short* __restrict__ Vt,
                                                const int* __restrict__ attn_mask,
                                                const int* __restrict__ mask_future,
                                                unsigned short* ctx) {
  constexpr int KVB = 128;
  constexpr int LDK = 72;    // K tile [128][64+8]
  constexpr int LDV = 136;   // V tile d-major [64][128+8]
  __shared__ unsigned short Ksm[KVB * LDK];
  __shared__ unsigned short Vsm[64 * LDV];
#if !HAVE_MFMA16
  __shared__ unsigned short Psm[4][16 * LDV];
#endif
  __shared__ int s_any;
  const int tid = threadIdx.x, lane = tid & 63, wid = tid >> 6;
  const int l15 = lane & 15, l4 = lane >> 4;
  const int bh = blockIdx.y, b = bh >> 4;
  const int q0 = ((int)(blockIdx.x + blockIdx.y) & 31) * 64;   // diagonal swizzle
  const bool causal = (mask_future[0] != 0);

  if (tid == 0) s_any = 0;
  __syncthreads();
  for (int i = tid; i <= q0; i += 256)
    if (attn_mask[b * S_ + i]) s_any = 1;
  __syncthreads();
  const int kb_end = (causal && s_any) ? (q0 + 64) : S_;

  const unsigned short* Qb = Qh + (size_t)bh * S_ * HD_;
  const unsigned short* Kb = Kh + (size_t)bh * S_ * HD_;
  const unsigned short* Vb = Vt + (size_t)bh * HD_ * S_;
  const int* mrow = attn_mask + b * S_;

  const int qrow = q0 + wid * 16 + l15;   // this lane's q-row
  const bf16x8 qf0 = *reinterpret_cast<const bf16x8*>(&Qb[(size_t)qrow * HD_ + l4 * 8]);
  const bf16x8 qf1 = *reinterpret_cast<const bf16x8*>(&Qb[(size_t)qrow * HD_ + 32 + l4 * 8]);

  float m_run = -1e30f, l_run = 0.f;      // scalar state for q = l15
  f32x4 o[4] = {};                        // o[nf2][r]: q=wid*16+l4*4+r, d=nf2*16+l15

  bf16x8 kreg[4], vreg[4];
#pragma unroll
  for (int j = 0; j < 4; ++j) {
    const int idx = tid + 256 * j;
    kreg[j] = *reinterpret_cast<const bf16x8*>(&Kb[(size_t)(idx >> 3) * HD_ + (idx & 7) * 8]);
    vreg[j] = *reinterpret_cast<const bf16x8*>(&Vb[(size_t)(idx >> 4) * S_ + (idx & 15) * 8]);
  }

  for (int kb = 0; kb < kb_end; kb += KVB) {
    __syncthreads();
#pragma unroll
    for (int j = 0; j < 4; ++j) {
      const int idx = tid + 256 * j;
      *reinterpret_cast<bf16x8*>(&Ksm[(idx >> 3) * LDK + (idx & 7) * 8]) = kreg[j];
      *reinterpret_cast<bf16x8*>(&Vsm[(idx >> 4) * LDV + (idx & 15) * 8]) = vreg[j];
    }
    __syncthreads();

    if (kb + KVB < kb_end) {
      const int kn = kb + KVB;
#pragma unroll
      for (int j = 0; j < 4; ++j) {
        const int idx = tid + 256 * j;
        kreg[j] = *reinterpret_cast<const bf16x8*>(&Kb[(size_t)(kn + (idx >> 3)) * HD_ + (idx & 7) * 8]);
        vreg[j] = *reinterpret_cast<const bf16x8*>(&Vb[(size_t)(idx >> 4) * S_ + kn + (idx & 15) * 8]);
      }
    }

    // QK^T swapped: lane holds q=l15, keys nf*16+l4*4+r
    f32x4 sc[8];
#pragma unroll
    for (int nf = 0; nf < 8; ++nf) {
      bf16x8 kf0 = *reinterpret_cast<const bf16x8*>(&Ksm[(nf * 16 + l15) * LDK + l4 * 8]);
      bf16x8 kf1 = *reinterpret_cast<const bf16x8*>(&Ksm[(nf * 16 + l15) * LDK + 32 + l4 * 8]);
      f32x4 z = {};
      z = __builtin_amdgcn_mfma_f32_16x16x32_bf16(kf0, qf0, z, 0, 0, 0);
      z = __builtin_amdgcn_mfma_f32_16x16x32_bf16(kf1, qf1, z, 0, 0, 0);
      sc[nf] = z;
    }

    // lane-local softmax over this lane's 32 keys (row q = l15)
    float p[8][4];
    float mx = -1e30f;
#pragma unroll
    for (int nf = 0; nf < 8; ++nf) {
      const int4 mk4 = *reinterpret_cast<const int4*>(&mrow[kb + nf * 16 + l4 * 4]);
      const int kbase = kb + nf * 16 + l4 * 4;
#pragma unroll
      for (int r = 0; r < 4; ++r) {
        float vv = sc[nf][r] * 0.125f;
        if (causal && (kbase + r) > qrow) vv += NEGV;
        const int mkr = (r == 0) ? mk4.x : (r == 1) ? mk4.y : (r == 2) ? mk4.z : mk4.w;
        if (mkr == 0) vv = NEGV;
        p[nf][r] = vv;
        mx = fmaxf(mx, vv);
      }
    }
    mx = fmaxf(mx, __shfl_xor(mx, 16));
    mx = fmaxf(mx, __shfl_xor(mx, 32));
    const float m_new = fmaxf(m_run, mx);
    const float scale = __expf(m_run - m_new);
    float s_loc = 0.f;
#pragma unroll
    for (int nf = 0; nf < 8; ++nf)
#pragma unroll
      for (int r = 0; r < 4; ++r) {
        float e = __expf(p[nf][r] - m_new);
        p[nf][r] = e;
        s_loc += e;
      }
    s_loc += __shfl_xor(s_loc, 16);
    s_loc += __shfl_xor(s_loc, 32);
    l_run = l_run * scale + s_loc;
    m_run = m_new;

    float sq[4];
#pragma unroll
    for (int r = 0; r < 4; ++r) sq[r] = __shfl(scale, l4 * 4 + r);
#pragma unroll
    for (int nf2 = 0; nf2 < 4; ++nf2)
#pragma unroll
      for (int r = 0; r < 4; ++r) o[nf2][r] *= sq[r];

#if HAVE_MFMA16
    bf16x4 pk[8];
#pragma unroll
    for (int nf = 0; nf < 8; ++nf) {
      bf16x4 t;
      t[0] = (short)f2bf(p[nf][0]); t[1] = (short)f2bf(p[nf][1]);
      t[2] = (short)f2bf(p[nf][2]); t[3] = (short)f2bf(p[nf][3]);
      pk[nf] = t;
    }
#pragma unroll
    for (int nf2 = 0; nf2 < 4; ++nf2) {
#pragma unroll
      for (int nf = 0; nf < 8; ++nf) {
        bf16x4 vf = *reinterpret_cast<const bf16x4*>(&Vsm[(nf2 * 16 + l15) * LDV + nf * 16 + l4 * 4]);
        o[nf2] = __builtin_amdgcn_mfma_f32_16x16x16bf16_1k(pk[nf], vf, o[nf2], 0, 0, 0);
      }
    }
#else
    unsigned short* Pw = &Psm[wid][0];
#pragma unroll
    for (int nf = 0; nf < 8; ++nf)
#pragma unroll
      for (int r = 0; r < 4; ++r)
        Pw[l15 * LDV + nf * 16 + l4 * 4 + r] = f2bf(p[nf][r]);
#pragma unroll
    for (int nf2 = 0; nf2 < 4; ++nf2) {
#pragma unroll
      for (int kk = 0; kk < 4; ++kk) {
        bf16x8 pf = *reinterpret_cast<const bf16x8*>(&Pw[l15 * LDV + kk * 32 + l4 * 8]);
        bf16x8 vf = *reinterpret_cast<const bf16x8*>(&Vsm[(nf2 * 16 + l15) * LDV + kk * 32 + l4 * 8]);
        o[nf2] = __builtin_amdgcn_mfma_f32_16x16x32_bf16(pf, vf, o[nf2], 0, 0, 0);
      }
    }
#endif
  }

  const float linv = 1.f / l_run;
  float lq[4];
#pragma unroll
  for (int r = 0; r < 4; ++r) lq[r] = __shfl(linv, l4 * 4 + r);
#pragma unroll
  for (int nf2 = 0; nf2 < 4; ++nf2)
#pragma unroll
    for (int r = 0; r < 4; ++r) {
      const int rowg = q0 + wid * 16 + l4 * 4 + r;
      ctx[((size_t)bh * S_ + rowg) * HD_ + nf2 * 16 + l15] = f2bf(o[nf2][r] * lq[r]);
    }
}

extern "C" void kernel_launch(void* const* d_in, const int* in_sizes, int n_in,
                              void* d_out, int out_size, void* d_ws, size_t ws_size,
                              hipStream_t stream) {
  const float* q = (const float*)d_in[0];
  const float* k = (const float*)d_in[1];
  const float* v = (const float*)d_in[2];
  const int* attn_mask = (const int*)d_in[3];
  const float* Wq = (const float*)d_in[4];
  const float* Wk = (const float*)d_in[5];
  const float* Wv = (const float*)d_in[6];
  const float* Wo = (const float*)d_in[7];
  const int* mask_future = (const int*)d_in[8];

  // d_out is FLOAT32 (16.78 MB). ws usage: 16.78 MB.
  //   ws0: Qh bf16 -> ctx in place; ws1: Kh bf16; d_out first half: Vt bf16.
  const size_t n16 = (size_t)M_ * D_;
  unsigned short* ws0 = (unsigned short*)d_ws;
  unsigned short* ws1 = ws0 + n16;
  unsigned short* Vt  = (unsigned short*)d_out;
  float* out = (float*)d_out;
  (void)in_sizes; (void)n_in; (void)out_size; (void)ws_size;

  gemm_qkv3<<<dim3(8, 32, 3), 256, 0, stream>>>(q, k, v, Wq, Wk, Wv, ws0, ws1, Vt);
  attn_fwd<<<dim3(S_ / 64, B_ * H_), 256, 0, stream>>>(ws0, ws1, Vt, attn_mask, mask_future, ws0);
  gemm_oproj<<<dim3(8, 32), 256, 0, stream>>>(ws0, Wo, out);
}

// Round 13
// 181.027 us; speedup vs baseline: 2.0292x; 1.1215x over previous
//
#include <hip/hip_runtime.h>
#include <hip/hip_bf16.h>

typedef __attribute__((ext_vector_type(8))) short bf16x8;
typedef __attribute__((ext_vector_type(4))) short bf16x4;
typedef __attribute__((ext_vector_type(4))) float f32x4;

#define B_ 2
#define S_ 2048
#define D_ 1024
#define H_ 16
#define HD_ 64
#define M_ 4096
#define NEGV (-10000.0f)

#define NQ_ 4194304      // M_*D_ elems (q/k/v each)
#define NW_ 1048576      // D_*D_ elems (each W)

#if __has_builtin(__builtin_amdgcn_mfma_f32_16x16x16bf16_1k)
#define HAVE_MFMA16 1
#else
#define HAVE_MFMA16 0
#endif

static __device__ __forceinline__ unsigned short f2bf(float x) {
  __hip_bfloat16 h = __float2bfloat16(x);
  return *reinterpret_cast<unsigned short*>(&h);
}

static __device__ __forceinline__ bf16x8 cvt8(const float* p) {
  float4 a = *reinterpret_cast<const float4*>(p);
  float4 b = *reinterpret_cast<const float4*>(p + 4);
  bf16x8 r;
  r[0] = (short)f2bf(a.x); r[1] = (short)f2bf(a.y);
  r[2] = (short)f2bf(a.z); r[3] = (short)f2bf(a.w);
  r[4] = (short)f2bf(b.x); r[5] = (short)f2bf(b.y);
  r[6] = (short)f2bf(b.z); r[7] = (short)f2bf(b.w);
  return r;
}

// 16B global -> LDS DMA (dest must be wave-uniform base + lane*16).
static __device__ __forceinline__ void gl_lds16(const unsigned short* g, unsigned short* l) {
#if __has_builtin(__builtin_amdgcn_global_load_lds)
  __builtin_amdgcn_global_load_lds(
      (const __attribute__((address_space(1))) unsigned int*)g,
      (__attribute__((address_space(3))) unsigned int*)l, 16, 0, 0);
#else
  *reinterpret_cast<bf16x8*>(l) = *reinterpret_cast<const bf16x8*>(g);
#endif
}

// =================== FAST PATH (needs ws >= 50.3 MB) ===================

// f32 -> bf16 convert: q,k,v,Wq,Wk,Wv,Wo -> one contiguous bf16 region.
__global__ __launch_bounds__(256) void cvt_all(const float* __restrict__ q,
                                               const float* __restrict__ k,
                                               const float* __restrict__ v,
                                               const float* __restrict__ wq,
                                               const float* __restrict__ wk,
                                               const float* __restrict__ wv,
                                               const float* __restrict__ wo,
                                               unsigned short* __restrict__ dst) {
  for (size_t c = (size_t)blockIdx.x * 256 + threadIdx.x; c < 2097152; c += (size_t)2048 * 256) {
    const size_t e = c * 8;
    const float* s;
    if (e < (size_t)NQ_)            s = q  + e;
    else if (e < (size_t)2 * NQ_)   s = k  + (e - (size_t)NQ_);
    else if (e < (size_t)3 * NQ_)   s = v  + (e - (size_t)2 * NQ_);
    else if (e < (size_t)3 * NQ_ + NW_)     s = wq + (e - (size_t)3 * NQ_);
    else if (e < (size_t)3 * NQ_ + 2 * NW_) s = wk + (e - (size_t)3 * NQ_ - NW_);
    else if (e < (size_t)3 * NQ_ + 3 * NW_) s = wv + (e - (size_t)3 * NQ_ - 2 * NW_);
    else                                    s = wo + (e - (size_t)3 * NQ_ - 3 * NW_);
    *reinterpret_cast<bf16x8*>(dst + e) = cvt8(s);
  }
}

// gload_lds GEMM core: C128x128 = A(128,1024)bf16 @ B(128,1024)bf16^T.
// Linear [128][64] LDS tiles; XOR swizzle (col^=(row&7)<<3 elems) applied to
// the per-lane GLOBAL source (write side) and to the ds_read col (read side)
// -> frag reads are 2-way bank aliases (free) instead of 16-way.
template<bool HSPLIT>
static __device__ __forceinline__ void core_fast(const unsigned short* A,
                                                 const unsigned short* Bw,
                                                 unsigned short* Asm, unsigned short* Bsm,
                                                 int m0, int n0, f32x4 (*acc)[4]) {
  const int tid = threadIdx.x, lane = tid & 63, wid = tid >> 6;
  const int wm = wid >> 1, wn = wid & 1;
  const int l15 = lane & 15, l4 = lane >> 4;

  for (int k0 = 0; k0 < 1024; k0 += 64) {
    __syncthreads();                       // prior frag reads done
#pragma unroll
    for (int i = 0; i < 4; ++i) {
      const int idx = tid + 256 * i;
      const int row = idx >> 3;
      const int ce = ((idx & 7) * 8) ^ ((row & 7) << 3);   // swizzled elem col
      const unsigned short* ga;
      if constexpr (HSPLIT) {
        const int m = m0 + row, kk = k0 + ce;
        const int bb = m >> 11, s = m & 2047;
        ga = A + (((size_t)(bb * H_ + (kk >> 6)) * S_ + s) * HD_ + (kk & 63));
      } else {
        ga = A + (size_t)(m0 + row) * 1024 + k0 + ce;
      }
      gl_lds16(ga, Asm + (size_t)idx * 8);
      gl_lds16(Bw + (size_t)(n0 + row) * 1024 + k0 + ce, Bsm + (size_t)idx * 8);
    }
    __syncthreads();                       // vmcnt(0) drained by compiler
#pragma unroll
    for (int kk = 0; kk < 2; ++kk) {
      bf16x8 af[4], bfr[4];
#pragma unroll
      for (int f = 0; f < 4; ++f) {
        const int ra = wm * 64 + f * 16 + l15;
        const int ca = (kk * 32 + l4 * 8) ^ ((ra & 7) << 3);
        af[f] = *reinterpret_cast<const bf16x8*>(&Asm[ra * 64 + ca]);
        const int rb = wn * 64 + f * 16 + l15;
        const int cb = (kk * 32 + l4 * 8) ^ ((rb & 7) << 3);
        bfr[f] = *reinterpret_cast<const bf16x8*>(&Bsm[rb * 64 + cb]);
      }
#pragma unroll
      for (int fm = 0; fm < 4; ++fm)
#pragma unroll
        for (int fn = 0; fn < 4; ++fn)
          acc[fm][fn] = __builtin_amdgcn_mfma_f32_16x16x32_bf16(af[fm], bfr[fn], acc[fm][fn], 0, 0, 0);
    }
  }
}

__global__ __launch_bounds__(256) void gemm_qkv_fast(const unsigned short* __restrict__ qbf,
                                                     const unsigned short* __restrict__ kbf,
                                                     const unsigned short* __restrict__ vbf,
                                                     const unsigned short* __restrict__ wbf,
                                                     unsigned short* __restrict__ Qh,
                                                     unsigned short* __restrict__ Kh,
                                                     unsigned short* __restrict__ Vt) {
  __shared__ unsigned short Asm[128 * 64];
  __shared__ unsigned short Bsm[128 * 64];
  const int z = blockIdx.z;
  const unsigned short* A  = (z == 0) ? qbf : (z == 1) ? kbf : vbf;
  const unsigned short* Bw = wbf + (size_t)z * NW_;
  const int m0 = blockIdx.y * 128, n0 = blockIdx.x * 128;
  const int lane = threadIdx.x & 63, wid = threadIdx.x >> 6;
  const int wm = wid >> 1, wn = wid & 1;
  const int l15 = lane & 15, l4 = lane >> 4;
  f32x4 acc[4][4] = {};
  core_fast<false>(A, Bw, Asm, Bsm, m0, n0, acc);

#pragma unroll
  for (int fm = 0; fm < 4; ++fm) {
#pragma unroll
    for (int fn = 0; fn < 4; ++fn) {
      const int mg0 = m0 + wm * 64 + fm * 16 + l4 * 4;
      const int ng  = n0 + wn * 64 + fn * 16 + l15;
      const int bidx = mg0 >> 11, s = mg0 & 2047;
      const int h = ng >> 6, d = ng & 63;
      if (z < 2) {
        unsigned short* C = (z == 0) ? Qh : Kh;
#pragma unroll
        for (int r = 0; r < 4; ++r)
          C[((size_t)((bidx * H_ + h) * S_ + s + r)) * HD_ + d] = f2bf(acc[fm][fn][r]);
      } else {
        ushort4 pk;
        pk.x = f2bf(acc[fm][fn][0]); pk.y = f2bf(acc[fm][fn][1]);
        pk.z = f2bf(acc[fm][fn][2]); pk.w = f2bf(acc[fm][fn][3]);
        *reinterpret_cast<ushort4*>(&Vt[((size_t)((bidx * H_ + h) * HD_ + d)) * S_ + s]) = pk;
      }
    }
  }
}

__global__ __launch_bounds__(256) void gemm_o_fast(const unsigned short* __restrict__ ctx,
                                                   const unsigned short* __restrict__ wobf,
                                                   float* __restrict__ Cout) {
  __shared__ unsigned short Asm[128 * 64];
  __shared__ unsigned short Bsm[128 * 64];
  const int m0 = blockIdx.y * 128, n0 = blockIdx.x * 128;
  const int lane = threadIdx.x & 63, wid = threadIdx.x >> 6;
  const int wm = wid >> 1, wn = wid & 1;
  const int l15 = lane & 15, l4 = lane >> 4;
  f32x4 acc[4][4] = {};
  core_fast<true>(ctx, wobf, Asm, Bsm, m0, n0, acc);

#pragma unroll
  for (int fm = 0; fm < 4; ++fm)
#pragma unroll
    for (int fn = 0; fn < 4; ++fn) {
      const int mg0 = m0 + wm * 64 + fm * 16 + l4 * 4;
      const int ng  = n0 + wn * 64 + fn * 16 + l15;
#pragma unroll
      for (int r = 0; r < 4; ++r)
        Cout[(size_t)(mg0 + r) * 1024 + ng] = acc[fm][fn][r];
    }
}

// =================== FALLBACK PATH (round-12 kernels) ===================

template<bool AF32, bool BF32, bool HSPLIT>
static __device__ __forceinline__ void gemm_core(const void* Av, const void* Bv,
                                                 unsigned short* Asm, unsigned short* Bsm,
                                                 int m0, int n0, f32x4 (*acc)[4]) {
  constexpr int BK = 64, LDT = 72;
  constexpr int K = 1024;
  const int tid = threadIdx.x;
  const int lane = tid & 63, wid = tid >> 6;
  const int wm = wid >> 1, wn = wid & 1;
  const int l15 = lane & 15, l4 = lane >> 4;

  for (int k0 = 0; k0 < K; k0 += BK) {
    __syncthreads();
#pragma unroll
    for (int i = 0; i < 4; ++i) {
      int idx = tid + 256 * i;
      int row = idx >> 3, k8 = (idx & 7) * 8;
      bf16x8 va, vb;
      if constexpr (AF32) {
        va = cvt8((const float*)Av + (size_t)(m0 + row) * K + k0 + k8);
      } else if constexpr (HSPLIT) {
        const int m = m0 + row, kk = k0 + k8;
        const int bb = m >> 11, s = m & 2047;
        va = *reinterpret_cast<const bf16x8*>(
            (const unsigned short*)Av +
            (((size_t)(bb * H_ + (kk >> 6)) * S_ + s) * HD_ + (kk & 63)));
      } else {
        va = *reinterpret_cast<const bf16x8*>((const unsigned short*)Av + (size_t)(m0 + row) * K + k0 + k8);
      }
      if constexpr (BF32) {
        vb = cvt8((const float*)Bv + (size_t)(n0 + row) * K + k0 + k8);
      } else {
        vb = *reinterpret_cast<const bf16x8*>((const unsigned short*)Bv + (size_t)(n0 + row) * K + k0 + k8);
      }
      *reinterpret_cast<bf16x8*>(&Asm[row * LDT + k8]) = va;
      *reinterpret_cast<bf16x8*>(&Bsm[row * LDT + k8]) = vb;
    }
    __syncthreads();
#pragma unroll
    for (int kk = 0; kk < 2; ++kk) {
      bf16x8 af[4], bfr[4];
#pragma unroll
      for (int f = 0; f < 4; ++f) {
        af[f]  = *reinterpret_cast<const bf16x8*>(&Asm[(wm * 64 + f * 16 + l15) * LDT + kk * 32 + l4 * 8]);
        bfr[f] = *reinterpret_cast<const bf16x8*>(&Bsm[(wn * 64 + f * 16 + l15) * LDT + kk * 32 + l4 * 8]);
      }
#pragma unroll
      for (int fm = 0; fm < 4; ++fm)
#pragma unroll
        for (int fn = 0; fn < 4; ++fn)
          acc[fm][fn] = __builtin_amdgcn_mfma_f32_16x16x32_bf16(af[fm], bfr[fn], acc[fm][fn], 0, 0, 0);
    }
  }
}

__global__ __launch_bounds__(256) void gemm_qkv3(const float* __restrict__ q,
                                                 const float* __restrict__ k,
                                                 const float* __restrict__ v,
                                                 const float* __restrict__ Wq,
                                                 const float* __restrict__ Wk,
                                                 const float* __restrict__ Wv,
                                                 unsigned short* __restrict__ Qh,
                                                 unsigned short* __restrict__ Kh,
                                                 unsigned short* __restrict__ Vt) {
  constexpr int LDT = 72;
  __shared__ unsigned short Asm[128 * LDT];
  __shared__ unsigned short Bsm[128 * LDT];
  const int z = blockIdx.z;
  const float* A  = (z == 0) ? q  : (z == 1) ? k  : v;
  const float* Bw = (z == 0) ? Wq : (z == 1) ? Wk : Wv;
  const int m0 = blockIdx.y * 128, n0 = blockIdx.x * 128;
  const int lane = threadIdx.x & 63, wid = threadIdx.x >> 6;
  const int wm = wid >> 1, wn = wid & 1;
  const int l15 = lane & 15, l4 = lane >> 4;
  f32x4 acc[4][4] = {};
  gemm_core<true, true, false>(A, Bw, Asm, Bsm, m0, n0, acc);

#pragma unroll
  for (int fm = 0; fm < 4; ++fm) {
#pragma unroll
    for (int fn = 0; fn < 4; ++fn) {
      const int mg0 = m0 + wm * 64 + fm * 16 + l4 * 4;
      const int ng  = n0 + wn * 64 + fn * 16 + l15;
      const int bidx = mg0 >> 11, s = mg0 & 2047;
      const int h = ng >> 6, d = ng & 63;
      if (z < 2) {
        unsigned short* C = (z == 0) ? Qh : Kh;
#pragma unroll
        for (int r = 0; r < 4; ++r)
          C[((size_t)((bidx * H_ + h) * S_ + s + r)) * HD_ + d] = f2bf(acc[fm][fn][r]);
      } else {
        ushort4 pk;
        pk.x = f2bf(acc[fm][fn][0]); pk.y = f2bf(acc[fm][fn][1]);
        pk.z = f2bf(acc[fm][fn][2]); pk.w = f2bf(acc[fm][fn][3]);
        *reinterpret_cast<ushort4*>(&Vt[((size_t)((bidx * H_ + h) * HD_ + d)) * S_ + s]) = pk;
      }
    }
  }
}

__global__ __launch_bounds__(256) void gemm_oproj(const void* __restrict__ Av,
                                                  const void* __restrict__ Bv,
                                                  float* __restrict__ Cout) {
  constexpr int LDT = 72;
  __shared__ unsigned short Asm[128 * LDT];
  __shared__ unsigned short Bsm[128 * LDT];
  const int m0 = blockIdx.y * 128, n0 = blockIdx.x * 128;
  const int lane = threadIdx.x & 63, wid = threadIdx.x >> 6;
  const int wm = wid >> 1, wn = wid & 1;
  const int l15 = lane & 15, l4 = lane >> 4;
  f32x4 acc[4][4] = {};
  gemm_core<false, true, true>(Av, Bv, Asm, Bsm, m0, n0, acc);

#pragma unroll
  for (int fm = 0; fm < 4; ++fm)
#pragma unroll
    for (int fn = 0; fn < 4; ++fn) {
      const int mg0 = m0 + wm * 64 + fm * 16 + l4 * 4;
      const int ng  = n0 + wn * 64 + fn * 16 + l15;
#pragma unroll
      for (int r = 0; r < 4; ++r)
        Cout[(size_t)(mg0 + r) * 1024 + ng] = acc[fm][fn][r];
    }
}

// ============================ ATTENTION ============================
// Swapped QK^T, lane-local softmax, K=16 PV (round 11) + complement-pair
// XOR q-tile swizzle: the 4 blocks aliasing to one CU (stride-256) have
// q-tile indices {x^0, x^31, x^16, x^15} -> causal tile counts sum to 66
// for EVERY CU (diagonal swizzle gave 52..80).
__global__ __launch_bounds__(256) void attn_fwd(const unsigned short* Qh,
                                                const unsigned short* __restrict__ Kh,
                                                const unsigned short* __restrict__ Vt,
                                                const int* __restrict__ attn_mask,
                                                const int* __restrict__ mask_future,
                                                unsigned short* ctx) {
  constexpr int KVB = 128;
  constexpr int LDK = 72;    // K tile [128][64+8]
  constexpr int LDV = 136;   // V tile d-major [64][128+8]
  __shared__ unsigned short Ksm[KVB * LDK];
  __shared__ unsigned short Vsm[64 * LDV];
#if !HAVE_MFMA16
  __shared__ unsigned short Psm[4][16 * LDV];
#endif
  __shared__ int s_any;
  const int tid = threadIdx.x, lane = tid & 63, wid = tid >> 6;
  const int l15 = lane & 15, l4 = lane >> 4;
  const int bh = blockIdx.y, b = bh >> 4;
  const int tswz[4] = {0, 31, 16, 15};
  const int q0 = ((int)(blockIdx.x ^ tswz[(bh >> 3) & 3]) & 31) * 64;
  const bool causal = (mask_future[0] != 0);

  if (tid == 0) s_any = 0;
  __syncthreads();
  for (int i = tid; i <= q0; i += 256)
    if (attn_mask[b * S_ + i]) s_any = 1;
  __syncthreads();
  const int kb_end = (causal && s_any) ? (q0 + 64) : S_;

  const unsigned short* Qb = Qh + (size_t)bh * S_ * HD_;
  const unsigned short* Kb = Kh + (size_t)bh * S_ * HD_;
  const unsigned short* Vb = Vt + (size_t)bh * HD_ * S_;
  const int* mrow = attn_mask + b * S_;

  const int qrow = q0 + wid * 16 + l15;
  const bf16x8 qf0 = *reinterpret_cast<const bf16x8*>(&Qb[(size_t)qrow * HD_ + l4 * 8]);
  const bf16x8 qf1 = *reinterpret_cast<const bf16x8*>(&Qb[(size_t)qrow * HD_ + 32 + l4 * 8]);

  float m_run = -1e30f, l_run = 0.f;
  f32x4 o[4] = {};

  bf16x8 kreg[4], vreg[4];
#pragma unroll
  for (int j = 0; j < 4; ++j) {
    const int idx = tid + 256 * j;
    kreg[j] = *reinterpret_cast<const bf16x8*>(&Kb[(size_t)(idx >> 3) * HD_ + (idx & 7) * 8]);
    vreg[j] = *reinterpret_cast<const bf16x8*>(&Vb[(size_t)(idx >> 4) * S_ + (idx & 15) * 8]);
  }

  for (int kb = 0; kb < kb_end; kb += KVB) {
    __syncthreads();
#pragma unroll
    for (int j = 0; j < 4; ++j) {
      const int idx = tid + 256 * j;
      *reinterpret_cast<bf16x8*>(&Ksm[(idx >> 3) * LDK + (idx & 7) * 8]) = kreg[j];
      *reinterpret_cast<bf16x8*>(&Vsm[(idx >> 4) * LDV + (idx & 15) * 8]) = vreg[j];
    }
    __syncthreads();

    if (kb + KVB < kb_end) {
      const int kn = kb + KVB;
#pragma unroll
      for (int j = 0; j < 4; ++j) {
        const int idx = tid + 256 * j;
        kreg[j] = *reinterpret_cast<const bf16x8*>(&Kb[(size_t)(kn + (idx >> 3)) * HD_ + (idx & 7) * 8]);
        vreg[j] = *reinterpret_cast<const bf16x8*>(&Vb[(size_t)(idx >> 4) * S_ + kn + (idx & 15) * 8]);
      }
    }

    f32x4 sc[8];
#pragma unroll
    for (int nf = 0; nf < 8; ++nf) {
      bf16x8 kf0 = *reinterpret_cast<const bf16x8*>(&Ksm[(nf * 16 + l15) * LDK + l4 * 8]);
      bf16x8 kf1 = *reinterpret_cast<const bf16x8*>(&Ksm[(nf * 16 + l15) * LDK + 32 + l4 * 8]);
      f32x4 z = {};
      z = __builtin_amdgcn_mfma_f32_16x16x32_bf16(kf0, qf0, z, 0, 0, 0);
      z = __builtin_amdgcn_mfma_f32_16x16x32_bf16(kf1, qf1, z, 0, 0, 0);
      sc[nf] = z;
    }

    float p[8][4];
    float mx = -1e30f;
#pragma unroll
    for (int nf = 0; nf < 8; ++nf) {
      const int4 mk4 = *reinterpret_cast<const int4*>(&mrow[kb + nf * 16 + l4 * 4]);
      const int kbase = kb + nf * 16 + l4 * 4;
#pragma unroll
      for (int r = 0; r < 4; ++r) {
        float vv = sc[nf][r] * 0.125f;
        if (causal && (kbase + r) > qrow) vv += NEGV;
        const int mkr = (r == 0) ? mk4.x : (r == 1) ? mk4.y : (r == 2) ? mk4.z : mk4.w;
        if (mkr == 0) vv = NEGV;
        p[nf][r] = vv;
        mx = fmaxf(mx, vv);
      }
    }
    mx = fmaxf(mx, __shfl_xor(mx, 16));
    mx = fmaxf(mx, __shfl_xor(mx, 32));
    const float m_new = fmaxf(m_run, mx);
    const float scale = __expf(m_run - m_new);
    float s_loc = 0.f;
#pragma unroll
    for (int nf = 0; nf < 8; ++nf)
#pragma unroll
      for (int r = 0; r < 4; ++r) {
        float e = __expf(p[nf][r] - m_new);
        p[nf][r] = e;
        s_loc += e;
      }
    s_loc += __shfl_xor(s_loc, 16);
    s_loc += __shfl_xor(s_loc, 32);
    l_run = l_run * scale + s_loc;
    m_run = m_new;

    float sq[4];
#pragma unroll
    for (int r = 0; r < 4; ++r) sq[r] = __shfl(scale, l4 * 4 + r);
#pragma unroll
    for (int nf2 = 0; nf2 < 4; ++nf2)
#pragma unroll
      for (int r = 0; r < 4; ++r) o[nf2][r] *= sq[r];

#if HAVE_MFMA16
    bf16x4 pk[8];
#pragma unroll
    for (int nf = 0; nf < 8; ++nf) {
      bf16x4 t;
      t[0] = (short)f2bf(p[nf][0]); t[1] = (short)f2bf(p[nf][1]);
      t[2] = (short)f2bf(p[nf][2]); t[3] = (short)f2bf(p[nf][3]);
      pk[nf] = t;
    }
#pragma unroll
    for (int nf2 = 0; nf2 < 4; ++nf2) {
#pragma unroll
      for (int nf = 0; nf < 8; ++nf) {
        bf16x4 vf = *reinterpret_cast<const bf16x4*>(&Vsm[(nf2 * 16 + l15) * LDV + nf * 16 + l4 * 4]);
        o[nf2] = __builtin_amdgcn_mfma_f32_16x16x16bf16_1k(pk[nf], vf, o[nf2], 0, 0, 0);
      }
    }
#else
    unsigned short* Pw = &Psm[wid][0];
#pragma unroll
    for (int nf = 0; nf < 8; ++nf)
#pragma unroll
      for (int r = 0; r < 4; ++r)
        Pw[l15 * LDV + nf * 16 + l4 * 4 + r] = f2bf(p[nf][r]);
#pragma unroll
    for (int nf2 = 0; nf2 < 4; ++nf2) {
#pragma unroll
      for (int kk = 0; kk < 4; ++kk) {
        bf16x8 pf = *reinterpret_cast<const bf16x8*>(&Pw[l15 * LDV + kk * 32 + l4 * 8]);
        bf16x8 vf = *reinterpret_cast<const bf16x8*>(&Vsm[(nf2 * 16 + l15) * LDV + kk * 32 + l4 * 8]);
        o[nf2] = __builtin_amdgcn_mfma_f32_16x16x32_bf16(pf, vf, o[nf2], 0, 0, 0);
      }
    }
#endif
  }

  const float linv = 1.f / l_run;
  float lq[4];
#pragma unroll
  for (int r = 0; r < 4; ++r) lq[r] = __shfl(linv, l4 * 4 + r);
#pragma unroll
  for (int nf2 = 0; nf2 < 4; ++nf2)
#pragma unroll
    for (int r = 0; r < 4; ++r) {
      const int rowg = q0 + wid * 16 + l4 * 4 + r;
      ctx[((size_t)bh * S_ + rowg) * HD_ + nf2 * 16 + l15] = f2bf(o[nf2][r] * lq[r]);
    }
}

extern "C" void kernel_launch(void* const* d_in, const int* in_sizes, int n_in,
                              void* d_out, int out_size, void* d_ws, size_t ws_size,
                              hipStream_t stream) {
  const float* q = (const float*)d_in[0];
  const float* k = (const float*)d_in[1];
  const float* v = (const float*)d_in[2];
  const int* attn_mask = (const int*)d_in[3];
  const float* Wq = (const float*)d_in[4];
  const float* Wk = (const float*)d_in[5];
  const float* Wv = (const float*)d_in[6];
  const float* Wo = (const float*)d_in[7];
  const int* mask_future = (const int*)d_in[8];

  unsigned short* ws = (unsigned short*)d_ws;
  unsigned short* Vt = (unsigned short*)d_out;   // bf16 staging in f32 out buf
  float* out = (float*)d_out;
  (void)in_sizes; (void)n_in; (void)out_size;

  // Fast path needs: cvt region 16.78M elems (33.55 MB) + Qh + Kh (16.78 MB)
  const size_t CVT_ELEMS = (size_t)3 * NQ_ + 4 * NW_;          // 16777216
  const size_t NEED = (CVT_ELEMS + 2 * (size_t)NQ_) * 2;        // 50331648 B

  if (ws_size >= NEED) {
    unsigned short* cvt = ws;
    unsigned short* qbf = cvt;
    unsigned short* kbf = cvt + (size_t)NQ_;
    unsigned short* vbf = cvt + (size_t)2 * NQ_;
    unsigned short* wbf = cvt + (size_t)3 * NQ_;                // Wq,Wk,Wv,Wo
    unsigned short* Qh  = cvt + CVT_ELEMS;
    unsigned short* Kh  = Qh + (size_t)NQ_;

    cvt_all<<<2048, 256, 0, stream>>>(q, k, v, Wq, Wk, Wv, Wo, cvt);
    gemm_qkv_fast<<<dim3(8, 32, 3), 256, 0, stream>>>(qbf, kbf, vbf, wbf, Qh, Kh, Vt);
    attn_fwd<<<dim3(32, 32), 256, 0, stream>>>(Qh, Kh, Vt, attn_mask, mask_future, Qh);
    gemm_o_fast<<<dim3(8, 32), 256, 0, stream>>>(Qh, wbf + (size_t)3 * NW_, out);
  } else {
    unsigned short* Qh = ws;
    unsigned short* Kh = ws + (size_t)NQ_;
    gemm_qkv3<<<dim3(8, 32, 3), 256, 0, stream>>>(q, k, v, Wq, Wk, Wv, Qh, Kh, Vt);
    attn_fwd<<<dim3(32, 32), 256, 0, stream>>>(Qh, Kh, Vt, attn_mask, mask_future, Qh);
    gemm_oproj<<<dim3(8, 32), 256, 0, stream>>>(Qh, Wo, out);
  }
}

// Round 14
// 173.205 us; speedup vs baseline: 2.1208x; 1.0452x over previous
//
#include <hip/hip_runtime.h>
#include <hip/hip_bf16.h>

typedef __attribute__((ext_vector_type(8))) short bf16x8;
typedef __attribute__((ext_vector_type(4))) short bf16x4;
typedef __attribute__((ext_vector_type(4))) float f32x4;

#define B_ 2
#define S_ 2048
#define D_ 1024
#define H_ 16
#define HD_ 64
#define M_ 4096
#define NEGV (-10000.0f)

#define NQ_ 4194304      // M_*D_ elems (q/k/v each)
#define NW_ 1048576      // D_*D_ elems (each W)

#if __has_builtin(__builtin_amdgcn_mfma_f32_16x16x16bf16_1k)
#define HAVE_MFMA16 1
#else
#define HAVE_MFMA16 0
#endif

static __device__ __forceinline__ unsigned short f2bf(float x) {
  __hip_bfloat16 h = __float2bfloat16(x);
  return *reinterpret_cast<unsigned short*>(&h);
}

static __device__ __forceinline__ bf16x8 cvt8(const float* p) {
  float4 a = *reinterpret_cast<const float4*>(p);
  float4 b = *reinterpret_cast<const float4*>(p + 4);
  bf16x8 r;
  r[0] = (short)f2bf(a.x); r[1] = (short)f2bf(a.y);
  r[2] = (short)f2bf(a.z); r[3] = (short)f2bf(a.w);
  r[4] = (short)f2bf(b.x); r[5] = (short)f2bf(b.y);
  r[6] = (short)f2bf(b.z); r[7] = (short)f2bf(b.w);
  return r;
}

// 16B global -> LDS DMA (dest must be wave-uniform base + lane*16).
static __device__ __forceinline__ void gl_lds16(const unsigned short* g, unsigned short* l) {
#if __has_builtin(__builtin_amdgcn_global_load_lds)
  __builtin_amdgcn_global_load_lds(
      (const __attribute__((address_space(1))) unsigned int*)g,
      (__attribute__((address_space(3))) unsigned int*)l, 16, 0, 0);
#else
  *reinterpret_cast<bf16x8*>(l) = *reinterpret_cast<const bf16x8*>(g);
#endif
}

// =================== FAST PATH (needs ws >= 50.3 MB) ===================

__global__ __launch_bounds__(256) void cvt_all(const float* __restrict__ q,
                                               const float* __restrict__ k,
                                               const float* __restrict__ v,
                                               const float* __restrict__ wq,
                                               const float* __restrict__ wk,
                                               const float* __restrict__ wv,
                                               const float* __restrict__ wo,
                                               unsigned short* __restrict__ dst) {
  for (size_t c = (size_t)blockIdx.x * 256 + threadIdx.x; c < 2097152; c += (size_t)2048 * 256) {
    const size_t e = c * 8;
    const float* s;
    if (e < (size_t)NQ_)            s = q  + e;
    else if (e < (size_t)2 * NQ_)   s = k  + (e - (size_t)NQ_);
    else if (e < (size_t)3 * NQ_)   s = v  + (e - (size_t)2 * NQ_);
    else if (e < (size_t)3 * NQ_ + NW_)     s = wq + (e - (size_t)3 * NQ_);
    else if (e < (size_t)3 * NQ_ + 2 * NW_) s = wk + (e - (size_t)3 * NQ_ - NW_);
    else if (e < (size_t)3 * NQ_ + 3 * NW_) s = wv + (e - (size_t)3 * NQ_ - 2 * NW_);
    else                                    s = wo + (e - (size_t)3 * NQ_ - 3 * NW_);
    *reinterpret_cast<bf16x8*>(dst + e) = cvt8(s);
  }
}

template<bool HSPLIT>
static __device__ __forceinline__ void core_fast(const unsigned short* A,
                                                 const unsigned short* Bw,
                                                 unsigned short* Asm, unsigned short* Bsm,
                                                 int m0, int n0, f32x4 (*acc)[4]) {
  const int tid = threadIdx.x, lane = tid & 63, wid = tid >> 6;
  const int wm = wid >> 1, wn = wid & 1;
  const int l15 = lane & 15, l4 = lane >> 4;

  for (int k0 = 0; k0 < 1024; k0 += 64) {
    __syncthreads();
#pragma unroll
    for (int i = 0; i < 4; ++i) {
      const int idx = tid + 256 * i;
      const int row = idx >> 3;
      const int ce = ((idx & 7) * 8) ^ ((row & 7) << 3);   // swizzled elem col
      const unsigned short* ga;
      if constexpr (HSPLIT) {
        const int m = m0 + row, kk = k0 + ce;
        const int bb = m >> 11, s = m & 2047;
        ga = A + (((size_t)(bb * H_ + (kk >> 6)) * S_ + s) * HD_ + (kk & 63));
      } else {
        ga = A + (size_t)(m0 + row) * 1024 + k0 + ce;
      }
      gl_lds16(ga, Asm + (size_t)idx * 8);
      gl_lds16(Bw + (size_t)(n0 + row) * 1024 + k0 + ce, Bsm + (size_t)idx * 8);
    }
    __syncthreads();
#pragma unroll
    for (int kk = 0; kk < 2; ++kk) {
      bf16x8 af[4], bfr[4];
#pragma unroll
      for (int f = 0; f < 4; ++f) {
        const int ra = wm * 64 + f * 16 + l15;
        const int ca = (kk * 32 + l4 * 8) ^ ((ra & 7) << 3);
        af[f] = *reinterpret_cast<const bf16x8*>(&Asm[ra * 64 + ca]);
        const int rb = wn * 64 + f * 16 + l15;
        const int cb = (kk * 32 + l4 * 8) ^ ((rb & 7) << 3);
        bfr[f] = *reinterpret_cast<const bf16x8*>(&Bsm[rb * 64 + cb]);
      }
#pragma unroll
      for (int fm = 0; fm < 4; ++fm)
#pragma unroll
        for (int fn = 0; fn < 4; ++fn)
          acc[fm][fn] = __builtin_amdgcn_mfma_f32_16x16x32_bf16(af[fm], bfr[fn], acc[fm][fn], 0, 0, 0);
    }
  }
}

__global__ __launch_bounds__(256) void gemm_qkv_fast(const unsigned short* __restrict__ qbf,
                                                     const unsigned short* __restrict__ kbf,
                                                     const unsigned short* __restrict__ vbf,
                                                     const unsigned short* __restrict__ wbf,
                                                     unsigned short* __restrict__ Qh,
                                                     unsigned short* __restrict__ Kh,
                                                     unsigned short* __restrict__ Vt) {
  __shared__ unsigned short Asm[128 * 64];
  __shared__ unsigned short Bsm[128 * 64];
  const int z = blockIdx.z;
  const unsigned short* A  = (z == 0) ? qbf : (z == 1) ? kbf : vbf;
  const unsigned short* Bw = wbf + (size_t)z * NW_;
  const int m0 = blockIdx.y * 128, n0 = blockIdx.x * 128;
  const int lane = threadIdx.x & 63, wid = threadIdx.x >> 6;
  const int wm = wid >> 1, wn = wid & 1;
  const int l15 = lane & 15, l4 = lane >> 4;
  f32x4 acc[4][4] = {};
  core_fast<false>(A, Bw, Asm, Bsm, m0, n0, acc);

#pragma unroll
  for (int fm = 0; fm < 4; ++fm) {
#pragma unroll
    for (int fn = 0; fn < 4; ++fn) {
      const int mg0 = m0 + wm * 64 + fm * 16 + l4 * 4;
      const int ng  = n0 + wn * 64 + fn * 16 + l15;
      const int bidx = mg0 >> 11, s = mg0 & 2047;
      const int h = ng >> 6, d = ng & 63;
      if (z < 2) {
        unsigned short* C = (z == 0) ? Qh : Kh;
#pragma unroll
        for (int r = 0; r < 4; ++r)
          C[((size_t)((bidx * H_ + h) * S_ + s + r)) * HD_ + d] = f2bf(acc[fm][fn][r]);
      } else {
        ushort4 pk;
        pk.x = f2bf(acc[fm][fn][0]); pk.y = f2bf(acc[fm][fn][1]);
        pk.z = f2bf(acc[fm][fn][2]); pk.w = f2bf(acc[fm][fn][3]);
        *reinterpret_cast<ushort4*>(&Vt[((size_t)((bidx * H_ + h) * HD_ + d)) * S_ + s]) = pk;
      }
    }
  }
}

__global__ __launch_bounds__(256) void gemm_o_fast(const unsigned short* __restrict__ ctx,
                                                   const unsigned short* __restrict__ wobf,
                                                   float* __restrict__ Cout) {
  __shared__ unsigned short Asm[128 * 64];
  __shared__ unsigned short Bsm[128 * 64];
  const int m0 = blockIdx.y * 128, n0 = blockIdx.x * 128;
  const int lane = threadIdx.x & 63, wid = threadIdx.x >> 6;
  const int wm = wid >> 1, wn = wid & 1;
  const int l15 = lane & 15, l4 = lane >> 4;
  f32x4 acc[4][4] = {};
  core_fast<true>(ctx, wobf, Asm, Bsm, m0, n0, acc);

#pragma unroll
  for (int fm = 0; fm < 4; ++fm)
#pragma unroll
    for (int fn = 0; fn < 4; ++fn) {
      const int mg0 = m0 + wm * 64 + fm * 16 + l4 * 4;
      const int ng  = n0 + wn * 64 + fn * 16 + l15;
#pragma unroll
      for (int r = 0; r < 4; ++r)
        Cout[(size_t)(mg0 + r) * 1024 + ng] = acc[fm][fn][r];
    }
}

// =================== FALLBACK GEMMs (round-12) ===================

template<bool AF32, bool BF32, bool HSPLIT>
static __device__ __forceinline__ void gemm_core(const void* Av, const void* Bv,
                                                 unsigned short* Asm, unsigned short* Bsm,
                                                 int m0, int n0, f32x4 (*acc)[4]) {
  constexpr int BK = 64, LDT = 72;
  constexpr int K = 1024;
  const int tid = threadIdx.x;
  const int lane = tid & 63, wid = tid >> 6;
  const int wm = wid >> 1, wn = wid & 1;
  const int l15 = lane & 15, l4 = lane >> 4;

  for (int k0 = 0; k0 < K; k0 += BK) {
    __syncthreads();
#pragma unroll
    for (int i = 0; i < 4; ++i) {
      int idx = tid + 256 * i;
      int row = idx >> 3, k8 = (idx & 7) * 8;
      bf16x8 va, vb;
      if constexpr (AF32) {
        va = cvt8((const float*)Av + (size_t)(m0 + row) * K + k0 + k8);
      } else if constexpr (HSPLIT) {
        const int m = m0 + row, kk = k0 + k8;
        const int bb = m >> 11, s = m & 2047;
        va = *reinterpret_cast<const bf16x8*>(
            (const unsigned short*)Av +
            (((size_t)(bb * H_ + (kk >> 6)) * S_ + s) * HD_ + (kk & 63)));
      } else {
        va = *reinterpret_cast<const bf16x8*>((const unsigned short*)Av + (size_t)(m0 + row) * K + k0 + k8);
      }
      if constexpr (BF32) {
        vb = cvt8((const float*)Bv + (size_t)(n0 + row) * K + k0 + k8);
      } else {
        vb = *reinterpret_cast<const bf16x8*>((const unsigned short*)Bv + (size_t)(n0 + row) * K + k0 + k8);
      }
      *reinterpret_cast<bf16x8*>(&Asm[row * LDT + k8]) = va;
      *reinterpret_cast<bf16x8*>(&Bsm[row * LDT + k8]) = vb;
    }
    __syncthreads();
#pragma unroll
    for (int kk = 0; kk < 2; ++kk) {
      bf16x8 af[4], bfr[4];
#pragma unroll
      for (int f = 0; f < 4; ++f) {
        af[f]  = *reinterpret_cast<const bf16x8*>(&Asm[(wm * 64 + f * 16 + l15) * LDT + kk * 32 + l4 * 8]);
        bfr[f] = *reinterpret_cast<const bf16x8*>(&Bsm[(wn * 64 + f * 16 + l15) * LDT + kk * 32 + l4 * 8]);
      }
#pragma unroll
      for (int fm = 0; fm < 4; ++fm)
#pragma unroll
        for (int fn = 0; fn < 4; ++fn)
          acc[fm][fn] = __builtin_amdgcn_mfma_f32_16x16x32_bf16(af[fm], bfr[fn], acc[fm][fn], 0, 0, 0);
    }
  }
}

__global__ __launch_bounds__(256) void gemm_qkv3(const float* __restrict__ q,
                                                 const float* __restrict__ k,
                                                 const float* __restrict__ v,
                                                 const float* __restrict__ Wq,
                                                 const float* __restrict__ Wk,
                                                 const float* __restrict__ Wv,
                                                 unsigned short* __restrict__ Qh,
                                                 unsigned short* __restrict__ Kh,
                                                 unsigned short* __restrict__ Vt) {
  constexpr int LDT = 72;
  __shared__ unsigned short Asm[128 * LDT];
  __shared__ unsigned short Bsm[128 * LDT];
  const int z = blockIdx.z;
  const float* A  = (z == 0) ? q  : (z == 1) ? k  : v;
  const float* Bw = (z == 0) ? Wq : (z == 1) ? Wk : Wv;
  const int m0 = blockIdx.y * 128, n0 = blockIdx.x * 128;
  const int lane = threadIdx.x & 63, wid = threadIdx.x >> 6;
  const int wm = wid >> 1, wn = wid & 1;
  const int l15 = lane & 15, l4 = lane >> 4;
  f32x4 acc[4][4] = {};
  gemm_core<true, true, false>(A, Bw, Asm, Bsm, m0, n0, acc);

#pragma unroll
  for (int fm = 0; fm < 4; ++fm) {
#pragma unroll
    for (int fn = 0; fn < 4; ++fn) {
      const int mg0 = m0 + wm * 64 + fm * 16 + l4 * 4;
      const int ng  = n0 + wn * 64 + fn * 16 + l15;
      const int bidx = mg0 >> 11, s = mg0 & 2047;
      const int h = ng >> 6, d = ng & 63;
      if (z < 2) {
        unsigned short* C = (z == 0) ? Qh : Kh;
#pragma unroll
        for (int r = 0; r < 4; ++r)
          C[((size_t)((bidx * H_ + h) * S_ + s + r)) * HD_ + d] = f2bf(acc[fm][fn][r]);
      } else {
        ushort4 pk;
        pk.x = f2bf(acc[fm][fn][0]); pk.y = f2bf(acc[fm][fn][1]);
        pk.z = f2bf(acc[fm][fn][2]); pk.w = f2bf(acc[fm][fn][3]);
        *reinterpret_cast<ushort4*>(&Vt[((size_t)((bidx * H_ + h) * HD_ + d)) * S_ + s]) = pk;
      }
    }
  }
}

__global__ __launch_bounds__(256) void gemm_oproj(const void* __restrict__ Av,
                                                  const void* __restrict__ Bv,
                                                  float* __restrict__ Cout) {
  constexpr int LDT = 72;
  __shared__ unsigned short Asm[128 * LDT];
  __shared__ unsigned short Bsm[128 * LDT];
  const int m0 = blockIdx.y * 128, n0 = blockIdx.x * 128;
  const int lane = threadIdx.x & 63, wid = threadIdx.x >> 6;
  const int wm = wid >> 1, wn = wid & 1;
  const int l15 = lane & 15, l4 = lane >> 4;
  f32x4 acc[4][4] = {};
  gemm_core<false, true, true>(Av, Bv, Asm, Bsm, m0, n0, acc);

#pragma unroll
  for (int fm = 0; fm < 4; ++fm)
#pragma unroll
    for (int fn = 0; fn < 4; ++fn) {
      const int mg0 = m0 + wm * 64 + fm * 16 + l4 * 4;
      const int ng  = n0 + wn * 64 + fn * 16 + l15;
#pragma unroll
      for (int r = 0; r < 4; ++r)
        Cout[(size_t)(mg0 + r) * 1024 + ng] = acc[fm][fn][r];
    }
}

// ============================ ATTENTION ============================
// 2-wave (128-thread) blocks, QBLK=32, KVB=64: LDS 18.4 KB -> 8 blocks/CU,
// grid (64,32)=2048 blocks = ENTIRE GRID RESIDENT (16 waves/CU vs 5 avg).
// Depth-decay fix: co-CU blocks (same bx, by step 4) get q-tiles spread by
// q0t=(bx+9*by)&63 -> offsets {0,36,8,44,16,52,24,60}, staggered mix, no
// single-heavy-block tail. Swapped QK^T + lane-local softmax + K=16 PV.
__global__ __launch_bounds__(128) void attn_fwd(const unsigned short* Qh,
                                                const unsigned short* __restrict__ Kh,
                                                const unsigned short* __restrict__ Vt,
                                                const int* __restrict__ attn_mask,
                                                const int* __restrict__ mask_future,
                                                unsigned short* ctx) {
  constexpr int KVB = 64;
  constexpr int LDK = 72;    // K tile [64][64+8]
  constexpr int LDV = 72;    // V tile d-major [64][64+8]
  __shared__ unsigned short Ksm[KVB * LDK];
  __shared__ unsigned short Vsm[64 * LDV];
#if !HAVE_MFMA16
  __shared__ unsigned short Psm[2][16 * LDV];
#endif
  __shared__ int s_any;
  const int tid = threadIdx.x, lane = tid & 63, wid = tid >> 6;  // wid 0..1
  const int l15 = lane & 15, l4 = lane >> 4;
  const int bh = blockIdx.y, b = bh >> 4;
  const int q0t = (int)((blockIdx.x + 9 * blockIdx.y) & 63);
  const int q0 = q0t * 32;
  const bool causal = (mask_future[0] != 0);

  if (tid == 0) s_any = 0;
  __syncthreads();
  for (int i = tid; i <= q0; i += 128)
    if (attn_mask[b * S_ + i]) s_any = 1;
  __syncthreads();
  const int kb_end = (causal && s_any) ? (q0 + 32) : S_;

  const unsigned short* Qb = Qh + (size_t)bh * S_ * HD_;
  const unsigned short* Kb = Kh + (size_t)bh * S_ * HD_;
  const unsigned short* Vb = Vt + (size_t)bh * HD_ * S_;
  const int* mrow = attn_mask + b * S_;

  const int qrow = q0 + wid * 16 + l15;
  const bf16x8 qf0 = *reinterpret_cast<const bf16x8*>(&Qb[(size_t)qrow * HD_ + l4 * 8]);
  const bf16x8 qf1 = *reinterpret_cast<const bf16x8*>(&Qb[(size_t)qrow * HD_ + 32 + l4 * 8]);

  float m_run = -1e30f, l_run = 0.f;
  f32x4 o[4] = {};

  // prefetch: K 64x64 + V 64x64 = 512 chunks of 8 each; 128 thr -> 4 each
  bf16x8 kreg[4], vreg[4];
#pragma unroll
  for (int j = 0; j < 4; ++j) {
    const int idx = tid + 128 * j;
    kreg[j] = *reinterpret_cast<const bf16x8*>(&Kb[(size_t)(idx >> 3) * HD_ + (idx & 7) * 8]);
    vreg[j] = *reinterpret_cast<const bf16x8*>(&Vb[(size_t)(idx >> 3) * S_ + (idx & 7) * 8]);
  }

  for (int kb = 0; kb < kb_end; kb += KVB) {
    __syncthreads();
#pragma unroll
    for (int j = 0; j < 4; ++j) {
      const int idx = tid + 128 * j;
      *reinterpret_cast<bf16x8*>(&Ksm[(idx >> 3) * LDK + (idx & 7) * 8]) = kreg[j];
      *reinterpret_cast<bf16x8*>(&Vsm[(idx >> 3) * LDV + (idx & 7) * 8]) = vreg[j];
    }
    __syncthreads();

    if (kb + KVB < kb_end) {
      const int kn = kb + KVB;
#pragma unroll
      for (int j = 0; j < 4; ++j) {
        const int idx = tid + 128 * j;
        kreg[j] = *reinterpret_cast<const bf16x8*>(&Kb[(size_t)(kn + (idx >> 3)) * HD_ + (idx & 7) * 8]);
        vreg[j] = *reinterpret_cast<const bf16x8*>(&Vb[(size_t)(idx >> 3) * S_ + kn + (idx & 7) * 8]);
      }
    }

    // QK^T swapped: lane holds q=l15 (row qrow), keys nf*16+l4*4+r
    f32x4 sc[4];
#pragma unroll
    for (int nf = 0; nf < 4; ++nf) {
      bf16x8 kf0 = *reinterpret_cast<const bf16x8*>(&Ksm[(nf * 16 + l15) * LDK + l4 * 8]);
      bf16x8 kf1 = *reinterpret_cast<const bf16x8*>(&Ksm[(nf * 16 + l15) * LDK + 32 + l4 * 8]);
      f32x4 z = {};
      z = __builtin_amdgcn_mfma_f32_16x16x32_bf16(kf0, qf0, z, 0, 0, 0);
      z = __builtin_amdgcn_mfma_f32_16x16x32_bf16(kf1, qf1, z, 0, 0, 0);
      sc[nf] = z;
    }

    // lane-local softmax over this lane's 16 keys (row q = l15 of fragment)
    float p[4][4];
    float mx = -1e30f;
#pragma unroll
    for (int nf = 0; nf < 4; ++nf) {
      const int4 mk4 = *reinterpret_cast<const int4*>(&mrow[kb + nf * 16 + l4 * 4]);
      const int kbase = kb + nf * 16 + l4 * 4;
#pragma unroll
      for (int r = 0; r < 4; ++r) {
        float vv = sc[nf][r] * 0.125f;
        if (causal && (kbase + r) > qrow) vv += NEGV;
        const int mkr = (r == 0) ? mk4.x : (r == 1) ? mk4.y : (r == 2) ? mk4.z : mk4.w;
        if (mkr == 0) vv = NEGV;
        p[nf][r] = vv;
        mx = fmaxf(mx, vv);
      }
    }
    mx = fmaxf(mx, __shfl_xor(mx, 16));
    mx = fmaxf(mx, __shfl_xor(mx, 32));
    const float m_new = fmaxf(m_run, mx);
    const float scale = __expf(m_run - m_new);
    float s_loc = 0.f;
#pragma unroll
    for (int nf = 0; nf < 4; ++nf)
#pragma unroll
      for (int r = 0; r < 4; ++r) {
        float e = __expf(p[nf][r] - m_new);
        p[nf][r] = e;
        s_loc += e;
      }
    s_loc += __shfl_xor(s_loc, 16);
    s_loc += __shfl_xor(s_loc, 32);
    l_run = l_run * scale + s_loc;
    m_run = m_new;

    float sq[4];
#pragma unroll
    for (int r = 0; r < 4; ++r) sq[r] = __shfl(scale, l4 * 4 + r);
#pragma unroll
    for (int nf2 = 0; nf2 < 4; ++nf2)
#pragma unroll
      for (int r = 0; r < 4; ++r) o[nf2][r] *= sq[r];

#if HAVE_MFMA16
    bf16x4 pk[4];
#pragma unroll
    for (int nf = 0; nf < 4; ++nf) {
      bf16x4 t;
      t[0] = (short)f2bf(p[nf][0]); t[1] = (short)f2bf(p[nf][1]);
      t[2] = (short)f2bf(p[nf][2]); t[3] = (short)f2bf(p[nf][3]);
      pk[nf] = t;
    }
#pragma unroll
    for (int nf2 = 0; nf2 < 4; ++nf2) {
#pragma unroll
      for (int nf = 0; nf < 4; ++nf) {
        bf16x4 vf = *reinterpret_cast<const bf16x4*>(&Vsm[(nf2 * 16 + l15) * LDV + nf * 16 + l4 * 4]);
        o[nf2] = __builtin_amdgcn_mfma_f32_16x16x16bf16_1k(pk[nf], vf, o[nf2], 0, 0, 0);
      }
    }
#else
    unsigned short* Pw = &Psm[wid][0];
#pragma unroll
    for (int nf = 0; nf < 4; ++nf)
#pragma unroll
      for (int r = 0; r < 4; ++r)
        Pw[l15 * LDV + nf * 16 + l4 * 4 + r] = f2bf(p[nf][r]);
#pragma unroll
    for (int nf2 = 0; nf2 < 4; ++nf2) {
#pragma unroll
      for (int kk = 0; kk < 2; ++kk) {
        bf16x8 pf = *reinterpret_cast<const bf16x8*>(&Pw[l15 * LDV + kk * 32 + l4 * 8]);
        bf16x8 vf = *reinterpret_cast<const bf16x8*>(&Vsm[(nf2 * 16 + l15) * LDV + kk * 32 + l4 * 8]);
        o[nf2] = __builtin_amdgcn_mfma_f32_16x16x32_bf16(pf, vf, o[nf2], 0, 0, 0);
      }
    }
#endif
  }

  const float linv = 1.f / l_run;
  float lq[4];
#pragma unroll
  for (int r = 0; r < 4; ++r) lq[r] = __shfl(linv, l4 * 4 + r);
#pragma unroll
  for (int nf2 = 0; nf2 < 4; ++nf2)
#pragma unroll
    for (int r = 0; r < 4; ++r) {
      const int rowg = q0 + wid * 16 + l4 * 4 + r;
      ctx[((size_t)bh * S_ + rowg) * HD_ + nf2 * 16 + l15] = f2bf(o[nf2][r] * lq[r]);
    }
}

extern "C" void kernel_launch(void* const* d_in, const int* in_sizes, int n_in,
                              void* d_out, int out_size, void* d_ws, size_t ws_size,
                              hipStream_t stream) {
  const float* q = (const float*)d_in[0];
  const float* k = (const float*)d_in[1];
  const float* v = (const float*)d_in[2];
  const int* attn_mask = (const int*)d_in[3];
  const float* Wq = (const float*)d_in[4];
  const float* Wk = (const float*)d_in[5];
  const float* Wv = (const float*)d_in[6];
  const float* Wo = (const float*)d_in[7];
  const int* mask_future = (const int*)d_in[8];

  unsigned short* ws = (unsigned short*)d_ws;
  unsigned short* Vt = (unsigned short*)d_out;   // bf16 staging in f32 out buf
  float* out = (float*)d_out;
  (void)in_sizes; (void)n_in; (void)out_size;

  const size_t CVT_ELEMS = (size_t)3 * NQ_ + 4 * NW_;          // 16777216
  const size_t NEED = (CVT_ELEMS + 2 * (size_t)NQ_) * 2;        // 50331648 B

  if (ws_size >= NEED) {
    unsigned short* cvt = ws;
    unsigned short* qbf = cvt;
    unsigned short* kbf = cvt + (size_t)NQ_;
    unsigned short* vbf = cvt + (size_t)2 * NQ_;
    unsigned short* wbf = cvt + (size_t)3 * NQ_;                // Wq,Wk,Wv,Wo
    unsigned short* Qh  = cvt + CVT_ELEMS;
    unsigned short* Kh  = Qh + (size_t)NQ_;

    cvt_all<<<2048, 256, 0, stream>>>(q, k, v, Wq, Wk, Wv, Wo, cvt);
    gemm_qkv_fast<<<dim3(8, 32, 3), 256, 0, stream>>>(qbf, kbf, vbf, wbf, Qh, Kh, Vt);
    attn_fwd<<<dim3(64, 32), 128, 0, stream>>>(Qh, Kh, Vt, attn_mask, mask_future, Qh);
    gemm_o_fast<<<dim3(8, 32), 256, 0, stream>>>(Qh, wbf + (size_t)3 * NW_, out);
  } else {
    unsigned short* Qh = ws;
    unsigned short* Kh = ws + (size_t)NQ_;
    gemm_qkv3<<<dim3(8, 32, 3), 256, 0, stream>>>(q, k, v, Wq, Wk, Wv, Qh, Kh, Vt);
    attn_fwd<<<dim3(64, 32), 128, 0, stream>>>(Qh, Kh, Vt, attn_mask, mask_future, Qh);
    gemm_oproj<<<dim3(8, 32), 256, 0, stream>>>(Qh, Wo, out);
  }
}